// Round 1
// 960.674 us; speedup vs baseline: 1.0937x; 1.0937x over previous
//
#include <hip/hip_runtime.h>
#include <math.h>

#define B_   2
#define S_   1024
#define H_   2048
#define NH_  32
#define NKV_ 8
#define D_   64
#define I_   8192
#define LCK_ 3
#define M_   (B_ * S_)   // 2048 token rows

typedef unsigned short u16;
typedef unsigned int   u32;
typedef __attribute__((ext_vector_type(8))) short bf16x8;   // 8 bf16 (4 VGPRs)
typedef __attribute__((ext_vector_type(4))) float f32x4;
typedef __attribute__((ext_vector_type(2))) unsigned int u32x2;

// f32 -> bf16 round-to-nearest-even (finite inputs)
__device__ __forceinline__ u16 f2b(float f) {
  u32 u = __float_as_uint(f);
  u += 0x7fffu + ((u >> 16) & 1u);
  return (u16)(u >> 16);
}
__device__ __forceinline__ float b2f(u16 h) { return __uint_as_float(((u32)h) << 16); }

__device__ __forceinline__ void st_bf4(u16* p, float a, float b, float c, float d) {
  u32x2 v;
  v.x = (u32)f2b(a) | ((u32)f2b(b) << 16);
  v.y = (u32)f2b(c) | ((u32)f2b(d) << 16);
  *(u32x2*)p = v;
}

// pack 4 f32x4 -> two bf16x8
__device__ __forceinline__ void cvt16(const float4& a, const float4& b,
                                      const float4& c, const float4& d,
                                      bf16x8& lo, bf16x8& hi) {
  lo[0] = (short)f2b(a.x); lo[1] = (short)f2b(a.y); lo[2] = (short)f2b(a.z); lo[3] = (short)f2b(a.w);
  lo[4] = (short)f2b(b.x); lo[5] = (short)f2b(b.y); lo[6] = (short)f2b(b.z); lo[7] = (short)f2b(b.w);
  hi[0] = (short)f2b(c.x); hi[1] = (short)f2b(c.y); hi[2] = (short)f2b(c.z); hi[3] = (short)f2b(c.w);
  hi[4] = (short)f2b(d.x); hi[5] = (short)f2b(d.y); hi[6] = (short)f2b(d.z); hi[7] = (short)f2b(d.w);
}

// async global->LDS, 16B per lane; LDS dest = wave-uniform base + lane*16
__device__ __forceinline__ void async16(const void* g, void* l) {
  __builtin_amdgcn_global_load_lds(
      (const __attribute__((address_space(1))) unsigned int*)(uintptr_t)g,
      (__attribute__((address_space(3))) unsigned int*)(unsigned int)(uintptr_t)l,
      16, 0, 0);
}

// ---------------------------------------------------------------------------
// Kernel 1: fused RMSNorm(emb)+RMSNorm(hidden) -> x = concat([e,h]) as BF16
// ---------------------------------------------------------------------------
__global__ __launch_bounds__(256) void norm_concat_kernel(
    const float* __restrict__ emb, const float* __restrict__ hid,
    const float* __restrict__ w_e, const float* __restrict__ w_h,
    u16* __restrict__ x)
{
  const int row = blockIdx.x;
  const int t = threadIdx.x;
  const float* e = emb + (size_t)row * H_;
  const float* h = hid + (size_t)row * H_;

  const float4 ev0 = *(const float4*)&e[t * 4];
  const float4 ev1 = *(const float4*)&e[t * 4 + 1024];
  const float4 hv0 = *(const float4*)&h[t * 4];
  const float4 hv1 = *(const float4*)&h[t * 4 + 1024];

  float se = ev0.x*ev0.x + ev0.y*ev0.y + ev0.z*ev0.z + ev0.w*ev0.w
           + ev1.x*ev1.x + ev1.y*ev1.y + ev1.z*ev1.z + ev1.w*ev1.w;
  float sh = hv0.x*hv0.x + hv0.y*hv0.y + hv0.z*hv0.z + hv0.w*hv0.w
           + hv1.x*hv1.x + hv1.y*hv1.y + hv1.z*hv1.z + hv1.w*hv1.w;

  #pragma unroll
  for (int m = 1; m < 64; m <<= 1) {
    se += __shfl_xor(se, m);
    sh += __shfl_xor(sh, m);
  }
  __shared__ float red[8];
  const int wv = t >> 6;
  if ((t & 63) == 0) { red[wv] = se; red[4 + wv] = sh; }
  __syncthreads();
  se = red[0] + red[1] + red[2] + red[3];
  sh = red[4] + red[5] + red[6] + red[7];

  const float re = 1.0f / sqrtf(se * (1.0f / H_) + 1e-6f);
  const float rh = 1.0f / sqrtf(sh * (1.0f / H_) + 1e-6f);

  const float4 we0 = *(const float4*)&w_e[t * 4];
  const float4 we1 = *(const float4*)&w_e[t * 4 + 1024];
  const float4 wh0 = *(const float4*)&w_h[t * 4];
  const float4 wh1 = *(const float4*)&w_h[t * 4 + 1024];

  u16* xr = x + (size_t)row * (2 * H_);
  st_bf4(&xr[t * 4],        ev0.x*re*we0.x, ev0.y*re*we0.y, ev0.z*re*we0.z, ev0.w*re*we0.w);
  st_bf4(&xr[t * 4 + 1024], ev1.x*re*we1.x, ev1.y*re*we1.y, ev1.z*re*we1.z, ev1.w*re*we1.w);
  st_bf4(&xr[2048 + t * 4],        hv0.x*rh*wh0.x, hv0.y*rh*wh0.y, hv0.z*rh*wh0.z, hv0.w*rh*wh0.w);
  st_bf4(&xr[2048 + t * 4 + 1024], hv1.x*rh*wh1.x, hv1.y*rh*wh1.y, hv1.z*rh*wh1.z, hv1.w*rh*wh1.w);
}

// ---------------------------------------------------------------------------
// Kernel 2: RMSNorm f32 in -> BF16 out (post-attention norm)
// ---------------------------------------------------------------------------
__global__ __launch_bounds__(256) void rmsnorm_kernel(
    const float* __restrict__ in, const float* __restrict__ w, u16* __restrict__ outp)
{
  const int row = blockIdx.x;
  const int t = threadIdx.x;
  const float* p = in + (size_t)row * H_;
  const float4 v0 = *(const float4*)&p[t * 4];
  const float4 v1 = *(const float4*)&p[t * 4 + 1024];
  float s = v0.x*v0.x + v0.y*v0.y + v0.z*v0.z + v0.w*v0.w
          + v1.x*v1.x + v1.y*v1.y + v1.z*v1.z + v1.w*v1.w;
  #pragma unroll
  for (int m = 1; m < 64; m <<= 1) s += __shfl_xor(s, m);
  __shared__ float red[4];
  const int wv = t >> 6;
  if ((t & 63) == 0) red[wv] = s;
  __syncthreads();
  s = red[0] + red[1] + red[2] + red[3];
  const float rs = 1.0f / sqrtf(s * (1.0f / H_) + 1e-6f);

  const float4 w0 = *(const float4*)&w[t * 4];
  const float4 w1 = *(const float4*)&w[t * 4 + 1024];
  u16* orow = outp + (size_t)row * H_;
  st_bf4(&orow[t * 4],        v0.x*rs*w0.x, v0.y*rs*w0.y, v0.z*rs*w0.z, v0.w*rs*w0.w);
  st_bf4(&orow[t * 4 + 1024], v1.x*rs*w1.x, v1.y*rs*w1.y, v1.z*rs*w1.z, v1.w*rs*w1.w);
}

// ---------------------------------------------------------------------------
// Kernel 3: weight f32->bf16 converters
// convert6: wq|wk|wv|wo|wg|wu packed contiguously into dst (element order)
// ---------------------------------------------------------------------------
__global__ __launch_bounds__(256) void convert6_kernel(
    const float* __restrict__ wq, const float* __restrict__ wk, const float* __restrict__ wv,
    const float* __restrict__ wo, const float* __restrict__ wg, const float* __restrict__ wu,
    u16* __restrict__ dst)
{
  const size_t i8 = ((size_t)blockIdx.x * 256 + threadIdx.x) * 8;
  const float* s; size_t base;
  if      (i8 <  8388608) { s = wq; base = 0; }
  else if (i8 < 10485760) { s = wk; base = 8388608; }
  else if (i8 < 12582912) { s = wv; base = 10485760; }
  else if (i8 < 16777216) { s = wo; base = 12582912; }
  else if (i8 < 33554432) { s = wg; base = 16777216; }
  else                    { s = wu; base = 33554432; }
  const float4 a = *(const float4*)&s[i8 - base];
  const float4 b = *(const float4*)&s[i8 - base + 4];
  bf16x8 r;
  r[0] = (short)f2b(a.x); r[1] = (short)f2b(a.y); r[2] = (short)f2b(a.z); r[3] = (short)f2b(a.w);
  r[4] = (short)f2b(b.x); r[5] = (short)f2b(b.y); r[6] = (short)f2b(b.z); r[7] = (short)f2b(b.w);
  *(bf16x8*)&dst[i8] = r;
}

__global__ __launch_bounds__(256) void convert1_kernel(
    const float* __restrict__ src, u16* __restrict__ dst)
{
  const size_t i8 = ((size_t)blockIdx.x * 256 + threadIdx.x) * 8;
  const float4 a = *(const float4*)&src[i8];
  const float4 b = *(const float4*)&src[i8 + 4];
  bf16x8 r;
  r[0] = (short)f2b(a.x); r[1] = (short)f2b(a.y); r[2] = (short)f2b(a.z); r[3] = (short)f2b(a.w);
  r[4] = (short)f2b(b.x); r[5] = (short)f2b(b.y); r[6] = (short)f2b(b.z); r[7] = (short)f2b(b.w);
  *(bf16x8*)&dst[i8] = r;
}

// ---------------------------------------------------------------------------
// Kernel 4: BF16 MFMA NT-GEMM (m97 structure)  C[M,N] = A[M,K] * Bw[N,K]^T
// 128x128 tile, BK=32, 256 thr (4 waves, 2x2), wave = 4x4 of 16x16x32 MFMA.
// Split-K via blockIdx.z: slice kz covers K-range [kz*Kc,(kz+1)*Kc), writes
// C + kz*M*N (f32 partials for MODE 0). gridDim.z==1 => exact old behavior.
// MODE 0: f32 C = acc   MODE 1: f32 C = acc + Xf32
// MODE 2: bf16 C = acc  MODE 3: bf16 C = silu(Xbf16) * acc
// ---------------------------------------------------------------------------
template <int MODE>
__global__ __launch_bounds__(256) void gemm_bf16_kernel(
    const u16* __restrict__ A, const u16* __restrict__ Bw,
    void* Cv, const void* Xv, int M, int N, int K)
{
  __shared__ __align__(16) u16 As[128 * 32];
  __shared__ __align__(16) u16 Bs[128 * 32];
  const int t = threadIdx.x;
  const int lane = t & 63;
  const int w = t >> 6;
  const int wr = w >> 1, wc = w & 1;
  const int row0 = blockIdx.y * 128;
  const int col0 = blockIdx.x * 128;
  const int kz = blockIdx.z;
  const int Kc = K / (int)gridDim.z;   // per-slice K extent (stride stays K)

  f32x4 acc[4][4];
  #pragma unroll
  for (int i = 0; i < 4; ++i)
    #pragma unroll
    for (int j = 0; j < 4; ++j)
      #pragma unroll
      for (int r = 0; r < 4; ++r) acc[i][j][r] = 0.f;

  const int srow = lane >> 2;
  const int skc  = (lane & 3) * 8;
  const u16* Ag = A  + (size_t)(row0 + w * 32 + srow) * K + skc + (size_t)kz * Kc;
  const u16* Bg = Bw + (size_t)(col0 + w * 32 + srow) * K + skc + (size_t)kz * Kc;
  u16* AsW = &As[w * 32 * 32];
  u16* BsW = &Bs[w * 32 * 32];

  const int fr = lane & 15;
  const int fq = (lane >> 4) * 8;

  for (int k0 = 0; k0 < Kc; k0 += 32) {
    __syncthreads();
    async16(Ag + k0,                  AsW);
    async16(Ag + k0 + (size_t)16 * K, AsW + 16 * 32);
    async16(Bg + k0,                  BsW);
    async16(Bg + k0 + (size_t)16 * K, BsW + 16 * 32);
    __syncthreads();

    bf16x8 af[4], bfr[4];
    #pragma unroll
    for (int ti = 0; ti < 4; ++ti)
      af[ti] = *(const bf16x8*)&As[(wr * 64 + ti * 16 + fr) * 32 + fq];
    #pragma unroll
    for (int tj = 0; tj < 4; ++tj)
      bfr[tj] = *(const bf16x8*)&Bs[(wc * 64 + tj * 16 + fr) * 32 + fq];
    #pragma unroll
    for (int ti = 0; ti < 4; ++ti)
      #pragma unroll
      for (int tj = 0; tj < 4; ++tj)
        acc[ti][tj] = __builtin_amdgcn_mfma_f32_16x16x32_bf16(af[ti], bfr[tj], acc[ti][tj], 0, 0, 0);
  }

  float* Cf = (float*)Cv + (size_t)kz * ((size_t)M * N);
  u16*  Cb = (u16*)Cv;
  const float* Xf = (const float*)Xv;
  const u16*  Xb = (const u16*)Xv;
  const int rbase = (lane >> 4) * 4;
  const int cofs  = lane & 15;
  #pragma unroll
  for (int ti = 0; ti < 4; ++ti) {
    #pragma unroll
    for (int r = 0; r < 4; ++r) {
      const int gr = row0 + wr * 64 + ti * 16 + rbase + r;
      #pragma unroll
      for (int tj = 0; tj < 4; ++tj) {
        const int gc = col0 + wc * 64 + tj * 16 + cofs;
        const size_t off = (size_t)gr * N + gc;
        const float v = acc[ti][tj][r];
        if constexpr (MODE == 0) {
          Cf[off] = v;
        } else if constexpr (MODE == 1) {
          Cf[off] = v + Xf[off];
        } else if constexpr (MODE == 2) {
          Cb[off] = f2b(v);
        } else {
          const float g = b2f(Xb[off]);
          Cb[off] = f2b((g / (1.f + __expf(-g))) * v);
        }
      }
    }
  }
}

// ---------------------------------------------------------------------------
// Kernel 4b: split-K partial reduce. out = sum_{z<NP} p[z*nper + i] (+ resid).
// Memory-bound; float4 lanes. resid==nullptr skips the residual (uniform).
// ---------------------------------------------------------------------------
template <int NP>
__global__ __launch_bounds__(256) void reduce_kernel(
    const float* __restrict__ p, const float* __restrict__ resid,
    float* __restrict__ out, size_t nper)
{
  const size_t i = ((size_t)blockIdx.x * 256 + threadIdx.x) * 4;
  float4 s = *(const float4*)&p[i];
  #pragma unroll
  for (int z = 1; z < NP; ++z) {
    const float4 a = *(const float4*)&p[(size_t)z * nper + i];
    s.x += a.x; s.y += a.y; s.z += a.z; s.w += a.w;
  }
  if (resid) {
    const float4 r = *(const float4*)&resid[i];
    s.x += r.x; s.y += r.y; s.z += r.z; s.w += r.w;
  }
  *(float4*)&out[i] = s;
}

// ---------------------------------------------------------------------------
// Kernel 5: RoPE in-place on fused qkv f32 buffer [M][3072]
// q: cols h*64 (h<32); k: cols 2048 + kh*64 (kh<8). pair (i, i+32).
// ---------------------------------------------------------------------------
__global__ __launch_bounds__(256) void rope_kernel(
    float* __restrict__ qkv, const int* __restrict__ pid)
{
  const int idx = blockIdx.x * 256 + threadIdx.x;
  const int total = M_ * (NH_ + NKV_) * 32;   // 2,621,440
  if (idx >= total) return;
  const int row = idx / 1280;
  const int rem = idx - row * 1280;
  const int head = rem >> 5;
  const int i = rem & 31;
  const int col = (head < NH_) ? head * 64 : 2048 + (head - NH_) * 64;
  float* base = qkv + (size_t)row * 3072 + col;
  const int pos = pid[row] + LCK_;
  const float invf = powf(10000.0f, -(float)i * (1.0f / 32.0f));
  const float ang = (float)pos * invf;
  const float c  = cosf(ang);
  const float sn = sinf(ang);
  const float x0 = base[i];
  const float x1 = base[i + 32];
  base[i]      = x0 * c - x1 * sn;
  base[i + 32] = x1 * c + x0 * sn;
}

// ---------------------------------------------------------------------------
// Kernel 6: MFMA flash attention. Block = (b,h,qt): 64 q rows, 4 waves x 16.
// QK^T and PV via mfma_f32_16x16x32_bf16; K/V staged bf16 in LDS (V transposed),
// P round-trips LDS in A-layout. Rows padded to 72 u16 (144B: 16B-aligned,
// bank-rotated). Online softmax per wave. 3 diagonal extras merged at end.
// ---------------------------------------------------------------------------
__global__ __launch_bounds__(256) void attn_kernel(
    const float* __restrict__ qkv,
    const float* __restrict__ ck, const float* __restrict__ cv,
    u16* __restrict__ ao)
{
  const int bid = blockIdx.x;
  const int qt = bid & 15;
  const int bh = bid >> 4;
  const int h = bh & 31;
  const int b = bh >> 5;
  const int t = threadIdx.x;
  const int lane = t & 63;
  const int w = t >> 6;
  const int qbase = qt * 64;

  const int fr = lane & 15;            // A-frag m / B-frag n
  const int fq = (lane >> 4) * 8;      // frag k base
  const int rbase = (lane >> 4) * 4;   // C-layout row base
  const int cofs = lane & 15;          // C-layout col

  __shared__ __align__(16) u16 Qs[64 * 72];    // [qrow][d], pre-scaled bf16
  __shared__ __align__(16) u16 Ks[64 * 72];    // [key][d]
  __shared__ __align__(16) u16 Vts[64 * 72];   // [d][key]
  __shared__ __align__(16) u16 Ps[64 * 72];    // [qrow][key] per-wave slices
  __shared__ float Ls[192];

  const size_t bh_off = (size_t)b * NH_ + h;
  const float* K0 = ck + bh_off * S_ * D_;
  const float* V0 = cv + bh_off * S_ * D_;

  // stage Q once: thread t -> row sr = t>>2, d-chunk sc = (t&3)*16
  const int sr = t >> 2;
  const int sc = (t & 3) * 16;
  {
    const float* qg = qkv + (size_t)(b * S_ + qbase + sr) * 3072 + h * 64 + sc;
    float4 a = *(const float4*)&qg[0], bb = *(const float4*)&qg[4],
           c = *(const float4*)&qg[8], d = *(const float4*)&qg[12];
    a.x*=0.125f; a.y*=0.125f; a.z*=0.125f; a.w*=0.125f;
    bb.x*=0.125f; bb.y*=0.125f; bb.z*=0.125f; bb.w*=0.125f;
    c.x*=0.125f; c.y*=0.125f; c.z*=0.125f; c.w*=0.125f;
    d.x*=0.125f; d.y*=0.125f; d.z*=0.125f; d.w*=0.125f;
    bf16x8 lo, hi; cvt16(a, bb, c, d, lo, hi);
    *(bf16x8*)&Qs[sr * 72 + sc] = lo;
    *(bf16x8*)&Qs[sr * 72 + sc + 8] = hi;
  }

  float m_r[4], l_r[4];
  f32x4 Oacc[4];
  #pragma unroll
  for (int r = 0; r < 4; ++r) { m_r[r] = -3.0e38f; l_r[r] = 0.f; }
  #pragma unroll
  for (int dt = 0; dt < 4; ++dt)
    #pragma unroll
    for (int r = 0; r < 4; ++r) Oacc[dt][r] = 0.f;

  for (int kt = 0; kt <= qt; ++kt) {
    __syncthreads();   // prior QK/PV reads of Ks/Vts done
    {
      const float* kg = K0 + (size_t)(kt * 64 + sr) * D_ + sc;
      float4 a = *(const float4*)&kg[0], bb = *(const float4*)&kg[4],
             c = *(const float4*)&kg[8], d = *(const float4*)&kg[12];
      bf16x8 lo, hi; cvt16(a, bb, c, d, lo, hi);
      *(bf16x8*)&Ks[sr * 72 + sc] = lo;
      *(bf16x8*)&Ks[sr * 72 + sc + 8] = hi;
      const float* vg = V0 + (size_t)(kt * 64 + sr) * D_ + sc;
      float4 va = *(const float4*)&vg[0], vb4 = *(const float4*)&vg[4],
             vc = *(const float4*)&vg[8], vd = *(const float4*)&vg[12];
      const float vv[16] = {va.x,va.y,va.z,va.w, vb4.x,vb4.y,vb4.z,vb4.w,
                            vc.x,vc.y,vc.z,vc.w, vd.x,vd.y,vd.z,vd.w};
      #pragma unroll
      for (int i = 0; i < 16; ++i) Vts[(sc + i) * 72 + sr] = f2b(vv[i]);
    }
    __syncthreads();   // staged tiles visible

    // ---- QK^T: wave w computes S[16 rows][64 keys] ----
    const bf16x8 qa0 = *(const bf16x8*)&Qs[(w * 16 + fr) * 72 + fq];
    const bf16x8 qa1 = *(const bf16x8*)&Qs[(w * 16 + fr) * 72 + 32 + fq];
    f32x4 sacc[4];
    #pragma unroll
    for (int nt = 0; nt < 4; ++nt) {
      const bf16x8 kb0 = *(const bf16x8*)&Ks[(nt * 16 + fr) * 72 + fq];
      const bf16x8 kb1 = *(const bf16x8*)&Ks[(nt * 16 + fr) * 72 + 32 + fq];
      f32x4 z; z[0]=0.f; z[1]=0.f; z[2]=0.f; z[3]=0.f;
      z = __builtin_amdgcn_mfma_f32_16x16x32_bf16(qa0, kb0, z, 0, 0, 0);
      sacc[nt] = __builtin_amdgcn_mfma_f32_16x16x32_bf16(qa1, kb1, z, 0, 0, 0);
    }
    if (kt == qt) {   // causal mask inside diagonal tile
      #pragma unroll
      for (int nt = 0; nt < 4; ++nt) {
        const int key = nt * 16 + cofs;
        #pragma unroll
        for (int r = 0; r < 4; ++r)
          if (key > w * 16 + rbase + r) sacc[nt][r] = -3.0e38f;
      }
    }

    // ---- online softmax (per wave, rows rbase..rbase+3 of wave's 16) ----
    #pragma unroll
    for (int r = 0; r < 4; ++r) {
      float rm = fmaxf(fmaxf(sacc[0][r], sacc[1][r]), fmaxf(sacc[2][r], sacc[3][r]));
      rm = fmaxf(rm, __shfl_xor(rm, 1));
      rm = fmaxf(rm, __shfl_xor(rm, 2));
      rm = fmaxf(rm, __shfl_xor(rm, 4));
      rm = fmaxf(rm, __shfl_xor(rm, 8));
      const float mnew = fmaxf(m_r[r], rm);
      const float alpha = __expf(m_r[r] - mnew);
      float p0 = __expf(sacc[0][r] - mnew);
      float p1 = __expf(sacc[1][r] - mnew);
      float p2 = __expf(sacc[2][r] - mnew);
      float p3 = __expf(sacc[3][r] - mnew);
      float rs = p0 + p1 + p2 + p3;
      rs += __shfl_xor(rs, 1);
      rs += __shfl_xor(rs, 2);
      rs += __shfl_xor(rs, 4);
      rs += __shfl_xor(rs, 8);
      l_r[r] = l_r[r] * alpha + rs;
      m_r[r] = mnew;
      #pragma unroll
      for (int dt = 0; dt < 4; ++dt) Oacc[dt][r] *= alpha;
      u16* prow = &Ps[(w * 16 + rbase + r) * 72 + cofs];
      prow[0]  = f2b(p0);
      prow[16] = f2b(p1);
      prow[32] = f2b(p2);
      prow[48] = f2b(p3);
    }

    // ---- PV: O[16 rows][64 d] += P @ V (wave-local P, block Vts) ----
    const bf16x8 pa0 = *(const bf16x8*)&Ps[(w * 16 + fr) * 72 + fq];
    const bf16x8 pa1 = *(const bf16x8*)&Ps[(w * 16 + fr) * 72 + 32 + fq];
    #pragma unroll
    for (int dt = 0; dt < 4; ++dt) {
      const bf16x8 vb0 = *(const bf16x8*)&Vts[(dt * 16 + fr) * 72 + fq];
      const bf16x8 vb1 = *(const bf16x8*)&Vts[(dt * 16 + fr) * 72 + 32 + fq];
      Oacc[dt] = __builtin_amdgcn_mfma_f32_16x16x32_bf16(pa0, vb0, Oacc[dt], 0, 0, 0);
      Oacc[dt] = __builtin_amdgcn_mfma_f32_16x16x32_bf16(pa1, vb1, Oacc[dt], 0, 0, 0);
    }
  }

  // ---- 3 diagonal extras: logits ----
  if (t < 192) {
    const int n = t >> 6;
    const int r = t & 63;
    const int qp = qbase + r;
    const float* kp;
    if (n < 2) kp = ck + ((((size_t)(n + 1) * B_ + b) * NH_ + h) * S_ + qp) * D_;
    else       kp = qkv + (size_t)(b * S_ + qp) * 3072 + 2048 + (h >> 2) * 64;
    float e = 0.f;
    #pragma unroll 16
    for (int d = 0; d < 64; ++d) e = fmaf(b2f(Qs[r * 72 + d]), kp[d], e);
    Ls[n * 64 + r] = e;
  }
  __syncthreads();

  // ---- merge extras + normalize + store bf16 ----
  #pragma unroll
  for (int r = 0; r < 4; ++r) {
    const int qr = w * 16 + rbase + r;
    const int qp = qbase + qr;
    const float e0 = Ls[qr], e1 = Ls[64 + qr], e2 = Ls[128 + qr];
    const float mnew = fmaxf(fmaxf(m_r[r], e0), fmaxf(e1, e2));
    const float alpha = __expf(m_r[r] - mnew);
    const float p0 = __expf(e0 - mnew);
    const float p1 = __expf(e1 - mnew);
    const float p2 = __expf(e2 - mnew);
    const float inv = 1.0f / (l_r[r] * alpha + p0 + p1 + p2);
    const float* v1p = cv + ((((size_t)1 * B_ + b) * NH_ + h) * S_ + qp) * D_;
    const float* v2p = cv + ((((size_t)2 * B_ + b) * NH_ + h) * S_ + qp) * D_;
    const float* v3p = qkv + (size_t)(b * S_ + qp) * 3072 + 2560 + (h >> 2) * 64;
    u16* aorow = ao + (size_t)(b * S_ + qp) * 2048 + h * 64;
    #pragma unroll
    for (int dt = 0; dt < 4; ++dt) {
      const int col = dt * 16 + cofs;
      const float o = (Oacc[dt][r] * alpha + p0 * v1p[col] + p1 * v2p[col] + p2 * v3p[col]) * inv;
      aorow[col] = f2b(o);
    }
  }
}

// ---------------------------------------------------------------------------
extern "C" void kernel_launch(void* const* d_in, const int* in_sizes, int n_in,
                              void* d_out, int out_size, void* d_ws, size_t ws_size,
                              hipStream_t stream)
{
  const float* input_emb = (const float*)d_in[0];
  const float* hidden    = (const float*)d_in[1];
  const float* cache_k   = (const float*)d_in[2];
  const float* cache_v   = (const float*)d_in[3];
  const int*   pos_ids   = (const int*)d_in[5];
  const float* wq = (const float*)d_in[6];
  const float* wk = (const float*)d_in[7];
  const float* wv = (const float*)d_in[8];
  const float* wo = (const float*)d_in[9];
  const float* wg = (const float*)d_in[10];
  const float* wu = (const float*)d_in[11];
  const float* wd = (const float*)d_in[12];
  const float* w_hidden_norm = (const float*)d_in[13];
  const float* w_input_ln    = (const float*)d_in[14];
  const float* w_post_ln     = (const float*)d_in[15];
  float* out = (float*)d_out;

  // Workspace (bytes), peak 167.8 MiB, lifetime-aliased:
  //  [0,25.2M)      wqkv_b (wq|wk|wv packed rows = 3072x4096)  -> dead after qkv GEMM
  //  [25.2,33.6M)   wo_b   -> dead after wo GEMM
  //  [33.6,67.1M)   wg_b   -> dead after gate GEMM; then wd_b
  //  [67.1,100.7M)  wu_b   -> dead after up GEMM; then down split-K partials (67M)
  //  [100.7,117.4M) x_b    -> dead after qkv GEMM; then wo partials; then hn
  //  [117.4,142.6M) qkvf f32 [M][3072] -> dead after attn; then gbb (33.5M)
  //  [142.6,151M)   qkv partial z=1 head; then ao bf16 -> dead after wo GEMM
  //  [151,167.8M)   qkv partial z=1 tail; then h2 f32 -> live to end
  char* wsb = (char*)d_ws;
  u16*   wall   = (u16*)(wsb + 0);
  u16*   wqkv_b = wall;
  u16*   wo_b   = (u16*)(wsb + 25165824);
  u16*   wg_b   = (u16*)(wsb + 33554432);
  u16*   wu_b   = (u16*)(wsb + 67108864);
  u16*   xb     = (u16*)(wsb + 100663296);
  float* qkvf   = (float*)(wsb + 117440512);
  u16*   ao     = (u16*)(wsb + 142606336);
  float* h2     = (float*)(wsb + 150994944);
  u16*   hn     = (u16*)(wsb + 100663296);   // alias x_b
  u16*   gbb    = (u16*)(wsb + 117440512);   // alias qkvf+ao
  u16*   gub    = (u16*)(wsb + 0);           // alias wqkv_b+wo_b
  u16*   wd_b   = (u16*)(wsb + 33554432);    // alias wg_b
  float* wo_p   = (float*)(wsb + 100663296); // wo split-K partials (2x16.8M, dead xb+qkvf)
  float* dn_p   = (float*)(wsb + 67108864);  // down split-K partials (4x16.8M, dead wu_b..gbb)

  // 1. weights -> bf16
  convert6_kernel<<<24576, 256, 0, stream>>>(wq, wk, wv, wo, wg, wu, wall);
  // 2. fused norms + concat -> bf16 x
  norm_concat_kernel<<<M_, 256, 0, stream>>>(input_emb, hidden, w_input_ln, w_hidden_norm, xb);
  // 3. fused QKV projection (N=3072), split-K=2 -> partials at qkvf (+M*N), reduce in place
  gemm_bf16_kernel<0><<<dim3(24, 16, 2), 256, 0, stream>>>(xb, wqkv_b, qkvf, nullptr, M_, 3072, 4096);
  reduce_kernel<2><<<6144, 256, 0, stream>>>(qkvf, nullptr, qkvf, (size_t)M_ * 3072);
  // 4. RoPE in-place on qkvf
  rope_kernel<<<10240, 256, 0, stream>>>(qkvf, pos_ids);
  // 5. MFMA flash attention -> bf16 ao
  attn_kernel<<<B_ * NH_ * (S_ / 64), 256, 0, stream>>>(qkvf, cache_k, cache_v, ao);
  // 6. output projection split-K=2 -> partials; reduce + residual(hidden) -> f32 h2
  gemm_bf16_kernel<0><<<dim3(16, 16, 2), 256, 0, stream>>>(ao, wo_b, wo_p, nullptr, M_, 2048, 2048);
  reduce_kernel<2><<<4096, 256, 0, stream>>>(wo_p, hidden, h2, (size_t)M_ * 2048);
  // 7. post-attention RMSNorm -> bf16 hn
  rmsnorm_kernel<<<M_, 256, 0, stream>>>(h2, w_post_ln, hn);
  // 8. gate GEMM -> bf16 gbb
  gemm_bf16_kernel<2><<<dim3(64, 16), 256, 0, stream>>>(hn, wg_b, gbb, nullptr, M_, 8192, 2048);
  // 9. wd -> bf16 (wg_b region now dead)
  convert1_kernel<<<8192, 256, 0, stream>>>(wd, wd_b);
  // 10. up GEMM, epilogue silu(gate)*up -> bf16 gub
  gemm_bf16_kernel<3><<<dim3(64, 16), 256, 0, stream>>>(hn, wu_b, gub, gbb, M_, 8192, 2048);
  // 11. down GEMM split-K=4 -> partials; reduce + residual(h2) -> out f32
  gemm_bf16_kernel<0><<<dim3(16, 16, 4), 256, 0, stream>>>(gub, wd_b, dn_p, nullptr, M_, 2048, 8192);
  reduce_kernel<4><<<4096, 256, 0, stream>>>(dn_p, h2, out, (size_t)M_ * 2048);
}

// Round 2
// 929.658 us; speedup vs baseline: 1.1302x; 1.0334x over previous
//
#include <hip/hip_runtime.h>
#include <math.h>

#define B_   2
#define S_   1024
#define H_   2048
#define NH_  32
#define NKV_ 8
#define D_   64
#define I_   8192
#define LCK_ 3
#define M_   (B_ * S_)   // 2048 token rows

typedef unsigned short u16;
typedef unsigned int   u32;
typedef __attribute__((ext_vector_type(8))) short bf16x8;   // 8 bf16 (4 VGPRs)
typedef __attribute__((ext_vector_type(4))) float f32x4;
typedef __attribute__((ext_vector_type(2))) unsigned int u32x2;

// f32 -> bf16 round-to-nearest-even (finite inputs)
__device__ __forceinline__ u16 f2b(float f) {
  u32 u = __float_as_uint(f);
  u += 0x7fffu + ((u >> 16) & 1u);
  return (u16)(u >> 16);
}
__device__ __forceinline__ float b2f(u16 h) { return __uint_as_float(((u32)h) << 16); }

__device__ __forceinline__ void st_bf4(u16* p, float a, float b, float c, float d) {
  u32x2 v;
  v.x = (u32)f2b(a) | ((u32)f2b(b) << 16);
  v.y = (u32)f2b(c) | ((u32)f2b(d) << 16);
  *(u32x2*)p = v;
}

// pack 4 f32x4 -> two bf16x8
__device__ __forceinline__ void cvt16(const float4& a, const float4& b,
                                      const float4& c, const float4& d,
                                      bf16x8& lo, bf16x8& hi) {
  lo[0] = (short)f2b(a.x); lo[1] = (short)f2b(a.y); lo[2] = (short)f2b(a.z); lo[3] = (short)f2b(a.w);
  lo[4] = (short)f2b(b.x); lo[5] = (short)f2b(b.y); lo[6] = (short)f2b(b.z); lo[7] = (short)f2b(b.w);
  hi[0] = (short)f2b(c.x); hi[1] = (short)f2b(c.y); hi[2] = (short)f2b(c.z); hi[3] = (short)f2b(c.w);
  hi[4] = (short)f2b(d.x); hi[5] = (short)f2b(d.y); hi[6] = (short)f2b(d.z); hi[7] = (short)f2b(d.w);
}

// async global->LDS, 16B per lane; LDS dest = wave-uniform base + lane*16
__device__ __forceinline__ void async16(const void* g, void* l) {
  __builtin_amdgcn_global_load_lds(
      (const __attribute__((address_space(1))) unsigned int*)(uintptr_t)g,
      (__attribute__((address_space(3))) unsigned int*)(unsigned int)(uintptr_t)l,
      16, 0, 0);
}

// ---------------------------------------------------------------------------
// Kernel 1: fused RMSNorm(emb)+RMSNorm(hidden) -> x = concat([e,h]) as BF16
// ---------------------------------------------------------------------------
__global__ __launch_bounds__(256) void norm_concat_kernel(
    const float* __restrict__ emb, const float* __restrict__ hid,
    const float* __restrict__ w_e, const float* __restrict__ w_h,
    u16* __restrict__ x)
{
  const int row = blockIdx.x;
  const int t = threadIdx.x;
  const float* e = emb + (size_t)row * H_;
  const float* h = hid + (size_t)row * H_;

  const float4 ev0 = *(const float4*)&e[t * 4];
  const float4 ev1 = *(const float4*)&e[t * 4 + 1024];
  const float4 hv0 = *(const float4*)&h[t * 4];
  const float4 hv1 = *(const float4*)&h[t * 4 + 1024];

  float se = ev0.x*ev0.x + ev0.y*ev0.y + ev0.z*ev0.z + ev0.w*ev0.w
           + ev1.x*ev1.x + ev1.y*ev1.y + ev1.z*ev1.z + ev1.w*ev1.w;
  float sh = hv0.x*hv0.x + hv0.y*hv0.y + hv0.z*hv0.z + hv0.w*hv0.w
           + hv1.x*hv1.x + hv1.y*hv1.y + hv1.z*hv1.z + hv1.w*hv1.w;

  #pragma unroll
  for (int m = 1; m < 64; m <<= 1) {
    se += __shfl_xor(se, m);
    sh += __shfl_xor(sh, m);
  }
  __shared__ float red[8];
  const int wv = t >> 6;
  if ((t & 63) == 0) { red[wv] = se; red[4 + wv] = sh; }
  __syncthreads();
  se = red[0] + red[1] + red[2] + red[3];
  sh = red[4] + red[5] + red[6] + red[7];

  const float re = 1.0f / sqrtf(se * (1.0f / H_) + 1e-6f);
  const float rh = 1.0f / sqrtf(sh * (1.0f / H_) + 1e-6f);

  const float4 we0 = *(const float4*)&w_e[t * 4];
  const float4 we1 = *(const float4*)&w_e[t * 4 + 1024];
  const float4 wh0 = *(const float4*)&w_h[t * 4];
  const float4 wh1 = *(const float4*)&w_h[t * 4 + 1024];

  u16* xr = x + (size_t)row * (2 * H_);
  st_bf4(&xr[t * 4],        ev0.x*re*we0.x, ev0.y*re*we0.y, ev0.z*re*we0.z, ev0.w*re*we0.w);
  st_bf4(&xr[t * 4 + 1024], ev1.x*re*we1.x, ev1.y*re*we1.y, ev1.z*re*we1.z, ev1.w*re*we1.w);
  st_bf4(&xr[2048 + t * 4],        hv0.x*rh*wh0.x, hv0.y*rh*wh0.y, hv0.z*rh*wh0.z, hv0.w*rh*wh0.w);
  st_bf4(&xr[2048 + t * 4 + 1024], hv1.x*rh*wh1.x, hv1.y*rh*wh1.y, hv1.z*rh*wh1.z, hv1.w*rh*wh1.w);
}

// ---------------------------------------------------------------------------
// Kernel 2: RMSNorm f32 in -> BF16 out (post-attention norm)
// ---------------------------------------------------------------------------
__global__ __launch_bounds__(256) void rmsnorm_kernel(
    const float* __restrict__ in, const float* __restrict__ w, u16* __restrict__ outp)
{
  const int row = blockIdx.x;
  const int t = threadIdx.x;
  const float* p = in + (size_t)row * H_;
  const float4 v0 = *(const float4*)&p[t * 4];
  const float4 v1 = *(const float4*)&p[t * 4 + 1024];
  float s = v0.x*v0.x + v0.y*v0.y + v0.z*v0.z + v0.w*v0.w
          + v1.x*v1.x + v1.y*v1.y + v1.z*v1.z + v1.w*v1.w;
  #pragma unroll
  for (int m = 1; m < 64; m <<= 1) s += __shfl_xor(s, m);
  __shared__ float red[4];
  const int wv = t >> 6;
  if ((t & 63) == 0) red[wv] = s;
  __syncthreads();
  s = red[0] + red[1] + red[2] + red[3];
  const float rs = 1.0f / sqrtf(s * (1.0f / H_) + 1e-6f);

  const float4 w0 = *(const float4*)&w[t * 4];
  const float4 w1 = *(const float4*)&w[t * 4 + 1024];
  u16* orow = outp + (size_t)row * H_;
  st_bf4(&orow[t * 4],        v0.x*rs*w0.x, v0.y*rs*w0.y, v0.z*rs*w0.z, v0.w*rs*w0.w);
  st_bf4(&orow[t * 4 + 1024], v1.x*rs*w1.x, v1.y*rs*w1.y, v1.z*rs*w1.z, v1.w*rs*w1.w);
}

// ---------------------------------------------------------------------------
// Kernel 3: weight f32->bf16 converters
// convert6: wq|wk|wv|wo|wg|wu packed contiguously into dst (element order)
// ---------------------------------------------------------------------------
__global__ __launch_bounds__(256) void convert6_kernel(
    const float* __restrict__ wq, const float* __restrict__ wk, const float* __restrict__ wv,
    const float* __restrict__ wo, const float* __restrict__ wg, const float* __restrict__ wu,
    u16* __restrict__ dst)
{
  const size_t i8 = ((size_t)blockIdx.x * 256 + threadIdx.x) * 8;
  const float* s; size_t base;
  if      (i8 <  8388608) { s = wq; base = 0; }
  else if (i8 < 10485760) { s = wk; base = 8388608; }
  else if (i8 < 12582912) { s = wv; base = 10485760; }
  else if (i8 < 16777216) { s = wo; base = 12582912; }
  else if (i8 < 33554432) { s = wg; base = 16777216; }
  else                    { s = wu; base = 33554432; }
  const float4 a = *(const float4*)&s[i8 - base];
  const float4 b = *(const float4*)&s[i8 - base + 4];
  bf16x8 r;
  r[0] = (short)f2b(a.x); r[1] = (short)f2b(a.y); r[2] = (short)f2b(a.z); r[3] = (short)f2b(a.w);
  r[4] = (short)f2b(b.x); r[5] = (short)f2b(b.y); r[6] = (short)f2b(b.z); r[7] = (short)f2b(b.w);
  *(bf16x8*)&dst[i8] = r;
}

__global__ __launch_bounds__(256) void convert1_kernel(
    const float* __restrict__ src, u16* __restrict__ dst)
{
  const size_t i8 = ((size_t)blockIdx.x * 256 + threadIdx.x) * 8;
  const float4 a = *(const float4*)&src[i8];
  const float4 b = *(const float4*)&src[i8 + 4];
  bf16x8 r;
  r[0] = (short)f2b(a.x); r[1] = (short)f2b(a.y); r[2] = (short)f2b(a.z); r[3] = (short)f2b(a.w);
  r[4] = (short)f2b(b.x); r[5] = (short)f2b(b.y); r[6] = (short)f2b(b.z); r[7] = (short)f2b(b.w);
  *(bf16x8*)&dst[i8] = r;
}

// ---------------------------------------------------------------------------
// Kernel 4: BF16 MFMA NT-GEMM, 2-phase double-buffered (T3-minimum pipeline).
// C[M,N] = A[M,K] * Bw[N,K]^T. 128x128 tile, BK=32, 256 thr (4 waves, 2x2),
// wave = 4x4 of 16x16x32 MFMA. Per iteration: issue STAGE(t+1) into the spare
// LDS buffer BEFORE ds_read+MFMA of tile t; single vmcnt(0)+barrier per tile
// (the __syncthreads drain) so prefetch latency hides under compute.
// Split-K via blockIdx.z: slice kz covers [kz*Kc,(kz+1)*Kc), MODE 0 writes
// partials at C + kz*M*N.
// MODE 0: f32 C = acc   MODE 1: f32 C = acc + Xf32
// MODE 2: bf16 C = acc  MODE 3: bf16 C = silu(Xbf16) * acc
// ---------------------------------------------------------------------------
template <int MODE>
__global__ __launch_bounds__(256) void gemm_bf16_kernel(
    const u16* __restrict__ A, const u16* __restrict__ Bw,
    void* Cv, const void* Xv, int M, int N, int K)
{
  __shared__ __align__(16) u16 As[2][128 * 32];
  __shared__ __align__(16) u16 Bs[2][128 * 32];
  const int t = threadIdx.x;
  const int lane = t & 63;
  const int w = t >> 6;
  const int wr = w >> 1, wc = w & 1;
  const int row0 = blockIdx.y * 128;
  const int col0 = blockIdx.x * 128;
  const int kz = blockIdx.z;
  const int Kc = K / (int)gridDim.z;   // per-slice K extent (stride stays K)

  f32x4 acc[4][4];
  #pragma unroll
  for (int i = 0; i < 4; ++i)
    #pragma unroll
    for (int j = 0; j < 4; ++j)
      #pragma unroll
      for (int r = 0; r < 4; ++r) acc[i][j][r] = 0.f;

  const int srow = lane >> 2;
  const int skc  = (lane & 3) * 8;
  const u16* Ag = A  + (size_t)(row0 + w * 32 + srow) * K + skc + (size_t)kz * Kc;
  const u16* Bg = Bw + (size_t)(col0 + w * 32 + srow) * K + skc + (size_t)kz * Kc;
  u16* AsW0 = &As[0][w * 32 * 32];
  u16* AsW1 = &As[1][w * 32 * 32];
  u16* BsW0 = &Bs[0][w * 32 * 32];
  u16* BsW1 = &Bs[1][w * 32 * 32];

  const int fr = lane & 15;
  const int fq = (lane >> 4) * 8;

  auto stage = [&](int k0, u16* aw, u16* bw) {
    async16(Ag + k0,                  aw);
    async16(Ag + k0 + (size_t)16 * K, aw + 16 * 32);
    async16(Bg + k0,                  bw);
    async16(Bg + k0 + (size_t)16 * K, bw + 16 * 32);
  };
  auto compute = [&](const u16* asb, const u16* bsb) {
    bf16x8 af[4], bfr[4];
    #pragma unroll
    for (int ti = 0; ti < 4; ++ti)
      af[ti] = *(const bf16x8*)&asb[(wr * 64 + ti * 16 + fr) * 32 + fq];
    #pragma unroll
    for (int tj = 0; tj < 4; ++tj)
      bfr[tj] = *(const bf16x8*)&bsb[(wc * 64 + tj * 16 + fr) * 32 + fq];
    #pragma unroll
    for (int ti = 0; ti < 4; ++ti)
      #pragma unroll
      for (int tj = 0; tj < 4; ++tj)
        acc[ti][tj] = __builtin_amdgcn_mfma_f32_16x16x32_bf16(af[ti], bfr[tj], acc[ti][tj], 0, 0, 0);
  };

  // prologue: tile 0 into buf0, drain, barrier
  stage(0, AsW0, BsW0);
  __syncthreads();

  int k0 = 0;
  for (;;) {
    // phase A: prefetch t+1 -> buf1 (buf1's readers finished before last barrier)
    if (k0 + 32 < Kc) stage(k0 + 32, AsW1, BsW1);
    compute(As[0], Bs[0]);
    if (k0 + 32 >= Kc) break;
    __syncthreads();   // vmcnt(0): buf1 resident; all buf0 reads retired
    // phase B: prefetch t+2 -> buf0
    if (k0 + 64 < Kc) stage(k0 + 64, AsW0, BsW0);
    compute(As[1], Bs[1]);
    if (k0 + 64 >= Kc) break;
    __syncthreads();
    k0 += 64;
  }

  float* Cf = (float*)Cv + (size_t)kz * ((size_t)M * N);
  u16*  Cb = (u16*)Cv;
  const float* Xf = (const float*)Xv;
  const u16*  Xb = (const u16*)Xv;
  const int rbase = (lane >> 4) * 4;
  const int cofs  = lane & 15;
  #pragma unroll
  for (int ti = 0; ti < 4; ++ti) {
    #pragma unroll
    for (int r = 0; r < 4; ++r) {
      const int gr = row0 + wr * 64 + ti * 16 + rbase + r;
      #pragma unroll
      for (int tj = 0; tj < 4; ++tj) {
        const int gc = col0 + wc * 64 + tj * 16 + cofs;
        const size_t off = (size_t)gr * N + gc;
        const float v = acc[ti][tj][r];
        if constexpr (MODE == 0) {
          Cf[off] = v;
        } else if constexpr (MODE == 1) {
          Cf[off] = v + Xf[off];
        } else if constexpr (MODE == 2) {
          Cb[off] = f2b(v);
        } else {
          const float g = b2f(Xb[off]);
          Cb[off] = f2b((g / (1.f + __expf(-g))) * v);
        }
      }
    }
  }
}

// ---------------------------------------------------------------------------
// Kernel 4b: split-K partial reduce. out = sum_{z<NP} p[z*nper + i] (+ resid).
// Memory-bound; float4 lanes. resid==nullptr skips the residual (uniform).
// ---------------------------------------------------------------------------
template <int NP>
__global__ __launch_bounds__(256) void reduce_kernel(
    const float* __restrict__ p, const float* __restrict__ resid,
    float* __restrict__ out, size_t nper)
{
  const size_t i = ((size_t)blockIdx.x * 256 + threadIdx.x) * 4;
  float4 s = *(const float4*)&p[i];
  #pragma unroll
  for (int z = 1; z < NP; ++z) {
    const float4 a = *(const float4*)&p[(size_t)z * nper + i];
    s.x += a.x; s.y += a.y; s.z += a.z; s.w += a.w;
  }
  if (resid) {
    const float4 r = *(const float4*)&resid[i];
    s.x += r.x; s.y += r.y; s.z += r.z; s.w += r.w;
  }
  *(float4*)&out[i] = s;
}

// ---------------------------------------------------------------------------
// Kernel 5: RoPE in-place on fused qkv f32 buffer [M][3072]
// q: cols h*64 (h<32); k: cols 2048 + kh*64 (kh<8). pair (i, i+32).
// ---------------------------------------------------------------------------
__global__ __launch_bounds__(256) void rope_kernel(
    float* __restrict__ qkv, const int* __restrict__ pid)
{
  const int idx = blockIdx.x * 256 + threadIdx.x;
  const int total = M_ * (NH_ + NKV_) * 32;   // 2,621,440
  if (idx >= total) return;
  const int row = idx / 1280;
  const int rem = idx - row * 1280;
  const int head = rem >> 5;
  const int i = rem & 31;
  const int col = (head < NH_) ? head * 64 : 2048 + (head - NH_) * 64;
  float* base = qkv + (size_t)row * 3072 + col;
  const int pos = pid[row] + LCK_;
  // 10000^(-i/32) = exp2(-i * log2(10000)/32); v_exp_f32 path, no libm powf
  const float invf = exp2f((float)i * (-13.2877123795494f / 32.0f));
  const float ang = (float)pos * invf;
  float sn, c;
  __sincosf(ang, &sn, &c);
  const float x0 = base[i];
  const float x1 = base[i + 32];
  base[i]      = x0 * c - x1 * sn;
  base[i + 32] = x1 * c + x0 * sn;
}

// ---------------------------------------------------------------------------
// Kernel 6: MFMA flash attention. Block = (b,h,qt): 64 q rows, 4 waves x 16.
// QK^T and PV via mfma_f32_16x16x32_bf16; K/V staged bf16 in LDS (V transposed),
// P round-trips LDS in A-layout. Rows padded to 72 u16 (144B: 16B-aligned,
// bank-rotated). Online softmax per wave. 3 diagonal extras merged at end.
// ---------------------------------------------------------------------------
__global__ __launch_bounds__(256) void attn_kernel(
    const float* __restrict__ qkv,
    const float* __restrict__ ck, const float* __restrict__ cv,
    u16* __restrict__ ao)
{
  const int bid = blockIdx.x;
  const int qt = bid & 15;
  const int bh = bid >> 4;
  const int h = bh & 31;
  const int b = bh >> 5;
  const int t = threadIdx.x;
  const int lane = t & 63;
  const int w = t >> 6;
  const int qbase = qt * 64;

  const int fr = lane & 15;            // A-frag m / B-frag n
  const int fq = (lane >> 4) * 8;      // frag k base
  const int rbase = (lane >> 4) * 4;   // C-layout row base
  const int cofs = lane & 15;          // C-layout col

  __shared__ __align__(16) u16 Qs[64 * 72];    // [qrow][d], pre-scaled bf16
  __shared__ __align__(16) u16 Ks[64 * 72];    // [key][d]
  __shared__ __align__(16) u16 Vts[64 * 72];   // [d][key]
  __shared__ __align__(16) u16 Ps[64 * 72];    // [qrow][key] per-wave slices
  __shared__ float Ls[192];

  const size_t bh_off = (size_t)b * NH_ + h;
  const float* K0 = ck + bh_off * S_ * D_;
  const float* V0 = cv + bh_off * S_ * D_;

  // stage Q once: thread t -> row sr = t>>2, d-chunk sc = (t&3)*16
  const int sr = t >> 2;
  const int sc = (t & 3) * 16;
  {
    const float* qg = qkv + (size_t)(b * S_ + qbase + sr) * 3072 + h * 64 + sc;
    float4 a = *(const float4*)&qg[0], bb = *(const float4*)&qg[4],
           c = *(const float4*)&qg[8], d = *(const float4*)&qg[12];
    a.x*=0.125f; a.y*=0.125f; a.z*=0.125f; a.w*=0.125f;
    bb.x*=0.125f; bb.y*=0.125f; bb.z*=0.125f; bb.w*=0.125f;
    c.x*=0.125f; c.y*=0.125f; c.z*=0.125f; c.w*=0.125f;
    d.x*=0.125f; d.y*=0.125f; d.z*=0.125f; d.w*=0.125f;
    bf16x8 lo, hi; cvt16(a, bb, c, d, lo, hi);
    *(bf16x8*)&Qs[sr * 72 + sc] = lo;
    *(bf16x8*)&Qs[sr * 72 + sc + 8] = hi;
  }

  float m_r[4], l_r[4];
  f32x4 Oacc[4];
  #pragma unroll
  for (int r = 0; r < 4; ++r) { m_r[r] = -3.0e38f; l_r[r] = 0.f; }
  #pragma unroll
  for (int dt = 0; dt < 4; ++dt)
    #pragma unroll
    for (int r = 0; r < 4; ++r) Oacc[dt][r] = 0.f;

  for (int kt = 0; kt <= qt; ++kt) {
    __syncthreads();   // prior QK/PV reads of Ks/Vts done
    {
      const float* kg = K0 + (size_t)(kt * 64 + sr) * D_ + sc;
      float4 a = *(const float4*)&kg[0], bb = *(const float4*)&kg[4],
             c = *(const float4*)&kg[8], d = *(const float4*)&kg[12];
      bf16x8 lo, hi; cvt16(a, bb, c, d, lo, hi);
      *(bf16x8*)&Ks[sr * 72 + sc] = lo;
      *(bf16x8*)&Ks[sr * 72 + sc + 8] = hi;
      const float* vg = V0 + (size_t)(kt * 64 + sr) * D_ + sc;
      float4 va = *(const float4*)&vg[0], vb4 = *(const float4*)&vg[4],
             vc = *(const float4*)&vg[8], vd = *(const float4*)&vg[12];
      const float vv[16] = {va.x,va.y,va.z,va.w, vb4.x,vb4.y,vb4.z,vb4.w,
                            vc.x,vc.y,vc.z,vc.w, vd.x,vd.y,vd.z,vd.w};
      #pragma unroll
      for (int i = 0; i < 16; ++i) Vts[(sc + i) * 72 + sr] = f2b(vv[i]);
    }
    __syncthreads();   // staged tiles visible

    // ---- QK^T: wave w computes S[16 rows][64 keys] ----
    const bf16x8 qa0 = *(const bf16x8*)&Qs[(w * 16 + fr) * 72 + fq];
    const bf16x8 qa1 = *(const bf16x8*)&Qs[(w * 16 + fr) * 72 + 32 + fq];
    f32x4 sacc[4];
    #pragma unroll
    for (int nt = 0; nt < 4; ++nt) {
      const bf16x8 kb0 = *(const bf16x8*)&Ks[(nt * 16 + fr) * 72 + fq];
      const bf16x8 kb1 = *(const bf16x8*)&Ks[(nt * 16 + fr) * 72 + 32 + fq];
      f32x4 z; z[0]=0.f; z[1]=0.f; z[2]=0.f; z[3]=0.f;
      z = __builtin_amdgcn_mfma_f32_16x16x32_bf16(qa0, kb0, z, 0, 0, 0);
      sacc[nt] = __builtin_amdgcn_mfma_f32_16x16x32_bf16(qa1, kb1, z, 0, 0, 0);
    }
    if (kt == qt) {   // causal mask inside diagonal tile
      #pragma unroll
      for (int nt = 0; nt < 4; ++nt) {
        const int key = nt * 16 + cofs;
        #pragma unroll
        for (int r = 0; r < 4; ++r)
          if (key > w * 16 + rbase + r) sacc[nt][r] = -3.0e38f;
      }
    }

    // ---- online softmax (per wave, rows rbase..rbase+3 of wave's 16) ----
    #pragma unroll
    for (int r = 0; r < 4; ++r) {
      float rm = fmaxf(fmaxf(sacc[0][r], sacc[1][r]), fmaxf(sacc[2][r], sacc[3][r]));
      rm = fmaxf(rm, __shfl_xor(rm, 1));
      rm = fmaxf(rm, __shfl_xor(rm, 2));
      rm = fmaxf(rm, __shfl_xor(rm, 4));
      rm = fmaxf(rm, __shfl_xor(rm, 8));
      const float mnew = fmaxf(m_r[r], rm);
      const float alpha = __expf(m_r[r] - mnew);
      float p0 = __expf(sacc[0][r] - mnew);
      float p1 = __expf(sacc[1][r] - mnew);
      float p2 = __expf(sacc[2][r] - mnew);
      float p3 = __expf(sacc[3][r] - mnew);
      float rs = p0 + p1 + p2 + p3;
      rs += __shfl_xor(rs, 1);
      rs += __shfl_xor(rs, 2);
      rs += __shfl_xor(rs, 4);
      rs += __shfl_xor(rs, 8);
      l_r[r] = l_r[r] * alpha + rs;
      m_r[r] = mnew;
      #pragma unroll
      for (int dt = 0; dt < 4; ++dt) Oacc[dt][r] *= alpha;
      u16* prow = &Ps[(w * 16 + rbase + r) * 72 + cofs];
      prow[0]  = f2b(p0);
      prow[16] = f2b(p1);
      prow[32] = f2b(p2);
      prow[48] = f2b(p3);
    }

    // ---- PV: O[16 rows][64 d] += P @ V (wave-local P, block Vts) ----
    const bf16x8 pa0 = *(const bf16x8*)&Ps[(w * 16 + fr) * 72 + fq];
    const bf16x8 pa1 = *(const bf16x8*)&Ps[(w * 16 + fr) * 72 + 32 + fq];
    #pragma unroll
    for (int dt = 0; dt < 4; ++dt) {
      const bf16x8 vb0 = *(const bf16x8*)&Vts[(dt * 16 + fr) * 72 + fq];
      const bf16x8 vb1 = *(const bf16x8*)&Vts[(dt * 16 + fr) * 72 + 32 + fq];
      Oacc[dt] = __builtin_amdgcn_mfma_f32_16x16x32_bf16(pa0, vb0, Oacc[dt], 0, 0, 0);
      Oacc[dt] = __builtin_amdgcn_mfma_f32_16x16x32_bf16(pa1, vb1, Oacc[dt], 0, 0, 0);
    }
  }

  // ---- 3 diagonal extras: logits ----
  if (t < 192) {
    const int n = t >> 6;
    const int r = t & 63;
    const int qp = qbase + r;
    const float* kp;
    if (n < 2) kp = ck + ((((size_t)(n + 1) * B_ + b) * NH_ + h) * S_ + qp) * D_;
    else       kp = qkv + (size_t)(b * S_ + qp) * 3072 + 2048 + (h >> 2) * 64;
    float e = 0.f;
    #pragma unroll 16
    for (int d = 0; d < 64; ++d) e = fmaf(b2f(Qs[r * 72 + d]), kp[d], e);
    Ls[n * 64 + r] = e;
  }
  __syncthreads();

  // ---- merge extras + normalize + store bf16 ----
  #pragma unroll
  for (int r = 0; r < 4; ++r) {
    const int qr = w * 16 + rbase + r;
    const int qp = qbase + qr;
    const float e0 = Ls[qr], e1 = Ls[64 + qr], e2 = Ls[128 + qr];
    const float mnew = fmaxf(fmaxf(m_r[r], e0), fmaxf(e1, e2));
    const float alpha = __expf(m_r[r] - mnew);
    const float p0 = __expf(e0 - mnew);
    const float p1 = __expf(e1 - mnew);
    const float p2 = __expf(e2 - mnew);
    const float inv = 1.0f / (l_r[r] * alpha + p0 + p1 + p2);
    const float* v1p = cv + ((((size_t)1 * B_ + b) * NH_ + h) * S_ + qp) * D_;
    const float* v2p = cv + ((((size_t)2 * B_ + b) * NH_ + h) * S_ + qp) * D_;
    const float* v3p = qkv + (size_t)(b * S_ + qp) * 3072 + 2560 + (h >> 2) * 64;
    u16* aorow = ao + (size_t)(b * S_ + qp) * 2048 + h * 64;
    #pragma unroll
    for (int dt = 0; dt < 4; ++dt) {
      const int col = dt * 16 + cofs;
      const float o = (Oacc[dt][r] * alpha + p0 * v1p[col] + p1 * v2p[col] + p2 * v3p[col]) * inv;
      aorow[col] = f2b(o);
    }
  }
}

// ---------------------------------------------------------------------------
extern "C" void kernel_launch(void* const* d_in, const int* in_sizes, int n_in,
                              void* d_out, int out_size, void* d_ws, size_t ws_size,
                              hipStream_t stream)
{
  const float* input_emb = (const float*)d_in[0];
  const float* hidden    = (const float*)d_in[1];
  const float* cache_k   = (const float*)d_in[2];
  const float* cache_v   = (const float*)d_in[3];
  const int*   pos_ids   = (const int*)d_in[5];
  const float* wq = (const float*)d_in[6];
  const float* wk = (const float*)d_in[7];
  const float* wv = (const float*)d_in[8];
  const float* wo = (const float*)d_in[9];
  const float* wg = (const float*)d_in[10];
  const float* wu = (const float*)d_in[11];
  const float* wd = (const float*)d_in[12];
  const float* w_hidden_norm = (const float*)d_in[13];
  const float* w_input_ln    = (const float*)d_in[14];
  const float* w_post_ln     = (const float*)d_in[15];
  float* out = (float*)d_out;

  // Workspace (bytes), peak 167.8 MiB, lifetime-aliased:
  //  [0,25.2M)      wqkv_b (wq|wk|wv packed rows = 3072x4096)  -> dead after qkv GEMM
  //  [25.2,33.6M)   wo_b   -> dead after wo GEMM
  //  [33.6,67.1M)   wg_b   -> dead after gate GEMM; then wd_b
  //  [67.1,100.7M)  wu_b   -> dead after up GEMM; then down split-K partials (67M)
  //  [100.7,117.4M) x_b    -> dead after qkv GEMM; then wo partials; then hn
  //  [117.4,142.6M) qkvf f32 [M][3072] -> dead after attn; then gbb (33.5M)
  //  [142.6,151M)   qkv partial z=1 head; then ao bf16 -> dead after wo GEMM
  //  [151,167.8M)   qkv partial z=1 tail; then h2 f32 -> live to end
  char* wsb = (char*)d_ws;
  u16*   wall   = (u16*)(wsb + 0);
  u16*   wqkv_b = wall;
  u16*   wo_b   = (u16*)(wsb + 25165824);
  u16*   wg_b   = (u16*)(wsb + 33554432);
  u16*   wu_b   = (u16*)(wsb + 67108864);
  u16*   xb     = (u16*)(wsb + 100663296);
  float* qkvf   = (float*)(wsb + 117440512);
  u16*   ao     = (u16*)(wsb + 142606336);
  float* h2     = (float*)(wsb + 150994944);
  u16*   hn     = (u16*)(wsb + 100663296);   // alias x_b
  u16*   gbb    = (u16*)(wsb + 117440512);   // alias qkvf+ao
  u16*   gub    = (u16*)(wsb + 0);           // alias wqkv_b+wo_b
  u16*   wd_b   = (u16*)(wsb + 33554432);    // alias wg_b
  float* wo_p   = (float*)(wsb + 100663296); // wo split-K partials (2x16.8M, dead xb+qkvf)
  float* dn_p   = (float*)(wsb + 67108864);  // down split-K partials (4x16.8M, dead wu_b..gbb)

  // 1. weights -> bf16
  convert6_kernel<<<24576, 256, 0, stream>>>(wq, wk, wv, wo, wg, wu, wall);
  // 2. fused norms + concat -> bf16 x
  norm_concat_kernel<<<M_, 256, 0, stream>>>(input_emb, hidden, w_input_ln, w_hidden_norm, xb);
  // 3. fused QKV projection (N=3072), split-K=2 -> partials at qkvf (+M*N), reduce in place
  gemm_bf16_kernel<0><<<dim3(24, 16, 2), 256, 0, stream>>>(xb, wqkv_b, qkvf, nullptr, M_, 3072, 4096);
  reduce_kernel<2><<<6144, 256, 0, stream>>>(qkvf, nullptr, qkvf, (size_t)M_ * 3072);
  // 4. RoPE in-place on qkvf
  rope_kernel<<<10240, 256, 0, stream>>>(qkvf, pos_ids);
  // 5. MFMA flash attention -> bf16 ao
  attn_kernel<<<B_ * NH_ * (S_ / 64), 256, 0, stream>>>(qkvf, cache_k, cache_v, ao);
  // 6. output projection split-K=2 -> partials; reduce + residual(hidden) -> f32 h2
  gemm_bf16_kernel<0><<<dim3(16, 16, 2), 256, 0, stream>>>(ao, wo_b, wo_p, nullptr, M_, 2048, 2048);
  reduce_kernel<2><<<4096, 256, 0, stream>>>(wo_p, hidden, h2, (size_t)M_ * 2048);
  // 7. post-attention RMSNorm -> bf16 hn
  rmsnorm_kernel<<<M_, 256, 0, stream>>>(h2, w_post_ln, hn);
  // 8. gate GEMM -> bf16 gbb
  gemm_bf16_kernel<2><<<dim3(64, 16), 256, 0, stream>>>(hn, wg_b, gbb, nullptr, M_, 8192, 2048);
  // 9. wd -> bf16 (wg_b region now dead)
  convert1_kernel<<<8192, 256, 0, stream>>>(wd, wd_b);
  // 10. up GEMM, epilogue silu(gate)*up -> bf16 gub
  gemm_bf16_kernel<3><<<dim3(64, 16), 256, 0, stream>>>(hn, wu_b, gub, gbb, M_, 8192, 2048);
  // 11. down GEMM split-K=4 -> partials; reduce + residual(h2) -> out f32
  gemm_bf16_kernel<0><<<dim3(16, 16, 4), 256, 0, stream>>>(gub, wd_b, dn_p, nullptr, M_, 2048, 8192);
  reduce_kernel<4><<<4096, 256, 0, stream>>>(dn_p, h2, out, (size_t)M_ * 2048);
}

// Round 3
// 878.629 us; speedup vs baseline: 1.1959x; 1.0581x over previous
//
#include <hip/hip_runtime.h>
#include <math.h>

#define B_   2
#define S_   1024
#define H_   2048
#define NH_  32
#define NKV_ 8
#define D_   64
#define I_   8192
#define LCK_ 3
#define M_   (B_ * S_)   // 2048 token rows

typedef unsigned short u16;
typedef unsigned int   u32;
typedef __attribute__((ext_vector_type(8))) short bf16x8;   // 8 bf16 (4 VGPRs)
typedef __attribute__((ext_vector_type(4))) float f32x4;
typedef __attribute__((ext_vector_type(2))) unsigned int u32x2;

// f32 -> bf16 round-to-nearest-even (finite inputs)
__device__ __forceinline__ u16 f2b(float f) {
  u32 u = __float_as_uint(f);
  u += 0x7fffu + ((u >> 16) & 1u);
  return (u16)(u >> 16);
}
__device__ __forceinline__ float b2f(u16 h) { return __uint_as_float(((u32)h) << 16); }

__device__ __forceinline__ void st_bf4(u16* p, float a, float b, float c, float d) {
  u32x2 v;
  v.x = (u32)f2b(a) | ((u32)f2b(b) << 16);
  v.y = (u32)f2b(c) | ((u32)f2b(d) << 16);
  *(u32x2*)p = v;
}

// pack 4 f32x4 -> two bf16x8
__device__ __forceinline__ void cvt16(const float4& a, const float4& b,
                                      const float4& c, const float4& d,
                                      bf16x8& lo, bf16x8& hi) {
  lo[0] = (short)f2b(a.x); lo[1] = (short)f2b(a.y); lo[2] = (short)f2b(a.z); lo[3] = (short)f2b(a.w);
  lo[4] = (short)f2b(b.x); lo[5] = (short)f2b(b.y); lo[6] = (short)f2b(b.z); lo[7] = (short)f2b(b.w);
  hi[0] = (short)f2b(c.x); hi[1] = (short)f2b(c.y); hi[2] = (short)f2b(c.z); hi[3] = (short)f2b(c.w);
  hi[4] = (short)f2b(d.x); hi[5] = (short)f2b(d.y); hi[6] = (short)f2b(d.z); hi[7] = (short)f2b(d.w);
}

// async global->LDS, 16B per lane; LDS dest = wave-uniform base + lane*16
__device__ __forceinline__ void async16(const void* g, void* l) {
  __builtin_amdgcn_global_load_lds(
      (const __attribute__((address_space(1))) unsigned int*)(uintptr_t)g,
      (__attribute__((address_space(3))) unsigned int*)(unsigned int)(uintptr_t)l,
      16, 0, 0);
}

// ---------------------------------------------------------------------------
// Kernel 1: fused RMSNorm(emb)+RMSNorm(hidden) -> x = concat([e,h]) as BF16
// ---------------------------------------------------------------------------
__global__ __launch_bounds__(256) void norm_concat_kernel(
    const float* __restrict__ emb, const float* __restrict__ hid,
    const float* __restrict__ w_e, const float* __restrict__ w_h,
    u16* __restrict__ x)
{
  const int row = blockIdx.x;
  const int t = threadIdx.x;
  const float* e = emb + (size_t)row * H_;
  const float* h = hid + (size_t)row * H_;

  const float4 ev0 = *(const float4*)&e[t * 4];
  const float4 ev1 = *(const float4*)&e[t * 4 + 1024];
  const float4 hv0 = *(const float4*)&h[t * 4];
  const float4 hv1 = *(const float4*)&h[t * 4 + 1024];

  float se = ev0.x*ev0.x + ev0.y*ev0.y + ev0.z*ev0.z + ev0.w*ev0.w
           + ev1.x*ev1.x + ev1.y*ev1.y + ev1.z*ev1.z + ev1.w*ev1.w;
  float sh = hv0.x*hv0.x + hv0.y*hv0.y + hv0.z*hv0.z + hv0.w*hv0.w
           + hv1.x*hv1.x + hv1.y*hv1.y + hv1.z*hv1.z + hv1.w*hv1.w;

  #pragma unroll
  for (int m = 1; m < 64; m <<= 1) {
    se += __shfl_xor(se, m);
    sh += __shfl_xor(sh, m);
  }
  __shared__ float red[8];
  const int wv = t >> 6;
  if ((t & 63) == 0) { red[wv] = se; red[4 + wv] = sh; }
  __syncthreads();
  se = red[0] + red[1] + red[2] + red[3];
  sh = red[4] + red[5] + red[6] + red[7];

  const float re = 1.0f / sqrtf(se * (1.0f / H_) + 1e-6f);
  const float rh = 1.0f / sqrtf(sh * (1.0f / H_) + 1e-6f);

  const float4 we0 = *(const float4*)&w_e[t * 4];
  const float4 we1 = *(const float4*)&w_e[t * 4 + 1024];
  const float4 wh0 = *(const float4*)&w_h[t * 4];
  const float4 wh1 = *(const float4*)&w_h[t * 4 + 1024];

  u16* xr = x + (size_t)row * (2 * H_);
  st_bf4(&xr[t * 4],        ev0.x*re*we0.x, ev0.y*re*we0.y, ev0.z*re*we0.z, ev0.w*re*we0.w);
  st_bf4(&xr[t * 4 + 1024], ev1.x*re*we1.x, ev1.y*re*we1.y, ev1.z*re*we1.z, ev1.w*re*we1.w);
  st_bf4(&xr[2048 + t * 4],        hv0.x*rh*wh0.x, hv0.y*rh*wh0.y, hv0.z*rh*wh0.z, hv0.w*rh*wh0.w);
  st_bf4(&xr[2048 + t * 4 + 1024], hv1.x*rh*wh1.x, hv1.y*rh*wh1.y, hv1.z*rh*wh1.z, hv1.w*rh*wh1.w);
}

// ---------------------------------------------------------------------------
// Kernel 2: RMSNorm f32 in -> BF16 out (post-attention norm)
// ---------------------------------------------------------------------------
__global__ __launch_bounds__(256) void rmsnorm_kernel(
    const float* __restrict__ in, const float* __restrict__ w, u16* __restrict__ outp)
{
  const int row = blockIdx.x;
  const int t = threadIdx.x;
  const float* p = in + (size_t)row * H_;
  const float4 v0 = *(const float4*)&p[t * 4];
  const float4 v1 = *(const float4*)&p[t * 4 + 1024];
  float s = v0.x*v0.x + v0.y*v0.y + v0.z*v0.z + v0.w*v0.w
          + v1.x*v1.x + v1.y*v1.y + v1.z*v1.z + v1.w*v1.w;
  #pragma unroll
  for (int m = 1; m < 64; m <<= 1) s += __shfl_xor(s, m);
  __shared__ float red[4];
  const int wv = t >> 6;
  if ((t & 63) == 0) red[wv] = s;
  __syncthreads();
  s = red[0] + red[1] + red[2] + red[3];
  const float rs = 1.0f / sqrtf(s * (1.0f / H_) + 1e-6f);

  const float4 w0 = *(const float4*)&w[t * 4];
  const float4 w1 = *(const float4*)&w[t * 4 + 1024];
  u16* orow = outp + (size_t)row * H_;
  st_bf4(&orow[t * 4],        v0.x*rs*w0.x, v0.y*rs*w0.y, v0.z*rs*w0.z, v0.w*rs*w0.w);
  st_bf4(&orow[t * 4 + 1024], v1.x*rs*w1.x, v1.y*rs*w1.y, v1.z*rs*w1.z, v1.w*rs*w1.w);
}

// ---------------------------------------------------------------------------
// Kernel 3: weight f32->bf16 converters
// convert6: wq|wk|wv|wo|wg|wu packed contiguously into dst (element order)
// ---------------------------------------------------------------------------
__global__ __launch_bounds__(256) void convert6_kernel(
    const float* __restrict__ wq, const float* __restrict__ wk, const float* __restrict__ wv,
    const float* __restrict__ wo, const float* __restrict__ wg, const float* __restrict__ wu,
    u16* __restrict__ dst)
{
  const size_t i8 = ((size_t)blockIdx.x * 256 + threadIdx.x) * 8;
  const float* s; size_t base;
  if      (i8 <  8388608) { s = wq; base = 0; }
  else if (i8 < 10485760) { s = wk; base = 8388608; }
  else if (i8 < 12582912) { s = wv; base = 10485760; }
  else if (i8 < 16777216) { s = wo; base = 12582912; }
  else if (i8 < 33554432) { s = wg; base = 16777216; }
  else                    { s = wu; base = 33554432; }
  const float4 a = *(const float4*)&s[i8 - base];
  const float4 b = *(const float4*)&s[i8 - base + 4];
  bf16x8 r;
  r[0] = (short)f2b(a.x); r[1] = (short)f2b(a.y); r[2] = (short)f2b(a.z); r[3] = (short)f2b(a.w);
  r[4] = (short)f2b(b.x); r[5] = (short)f2b(b.y); r[6] = (short)f2b(b.z); r[7] = (short)f2b(b.w);
  *(bf16x8*)&dst[i8] = r;
}

__global__ __launch_bounds__(256) void convert1_kernel(
    const float* __restrict__ src, u16* __restrict__ dst)
{
  const size_t i8 = ((size_t)blockIdx.x * 256 + threadIdx.x) * 8;
  const float4 a = *(const float4*)&src[i8];
  const float4 b = *(const float4*)&src[i8 + 4];
  bf16x8 r;
  r[0] = (short)f2b(a.x); r[1] = (short)f2b(a.y); r[2] = (short)f2b(a.z); r[3] = (short)f2b(a.w);
  r[4] = (short)f2b(b.x); r[5] = (short)f2b(b.y); r[6] = (short)f2b(b.z); r[7] = (short)f2b(b.w);
  *(bf16x8*)&dst[i8] = r;
}

// ---------------------------------------------------------------------------
// Kernel 4: BF16 MFMA NT-GEMM, depth-3 pipeline over 4 LDS buffers (T3+T4).
// C[M,N] = A[M,K] * Bw[N,K]^T. 128x128 tile, BK=32, 256 thr (4 waves, 2x2),
// wave = 4x4 of 16x16x32 MFMA.
// Main loop per tile t: counted s_waitcnt vmcnt(8) (tile t landed; t+1,t+2
// STAY IN FLIGHT across the barrier) -> raw s_barrier (no implicit drain) ->
// issue stage(t+3) into the buffer computed at t-1 -> compute tile t.
// WAR safety: lgkmcnt(0) before the barrier retires all prior ds_reads, so
// the refill target (read two phases ago by every wave) is quiescent.
// Buffer ring via rotating named pointers (no runtime-indexed arrays).
// Split-K via blockIdx.z: slice kz covers [kz*Kc,(kz+1)*Kc), MODE 0 writes
// partials at C + kz*M*N. Requires Kc % 32 == 0 and Kc/32 >= 3.
// MODE 0: f32 C = acc   MODE 1: f32 C = acc + Xf32
// MODE 2: bf16 C = acc  MODE 3: bf16 C = silu(Xbf16) * acc
// ---------------------------------------------------------------------------
template <int MODE>
__global__ __launch_bounds__(256) void gemm_bf16_kernel(
    const u16* __restrict__ A, const u16* __restrict__ Bw,
    void* Cv, const void* Xv, int M, int N, int K)
{
  __shared__ __align__(16) u16 As[4][128 * 32];   // 4 x 8 KB
  __shared__ __align__(16) u16 Bs[4][128 * 32];   // 4 x 8 KB  (64 KB total)
  const int t = threadIdx.x;
  const int lane = t & 63;
  const int w = t >> 6;
  const int wr = w >> 1, wc = w & 1;
  const int row0 = blockIdx.y * 128;
  const int col0 = blockIdx.x * 128;
  const int kz = blockIdx.z;
  const int Kc = K / (int)gridDim.z;   // per-slice K extent (stride stays K)
  const int nsteps = Kc >> 5;          // BK=32 tiles

  f32x4 acc[4][4];
  #pragma unroll
  for (int i = 0; i < 4; ++i)
    #pragma unroll
    for (int j = 0; j < 4; ++j)
      #pragma unroll
      for (int r = 0; r < 4; ++r) acc[i][j][r] = 0.f;

  const int srow = lane >> 2;
  const int skc  = (lane & 3) * 8;
  const u16* Ag = A  + (size_t)(row0 + w * 32 + srow) * K + skc + (size_t)kz * Kc;
  const u16* Bg = Bw + (size_t)(col0 + w * 32 + srow) * K + skc + (size_t)kz * Kc;
  const int wofs = w * 1024;           // per-wave 32x32 region within a buffer

  const int fr = lane & 15;
  const int fq = (lane >> 4) * 8;

  auto stageTo = [&](int k0, u16* ab, u16* bb) {
    async16(Ag + k0,                  ab + wofs);
    async16(Ag + k0 + (size_t)16 * K, ab + wofs + 512);
    async16(Bg + k0,                  bb + wofs);
    async16(Bg + k0 + (size_t)16 * K, bb + wofs + 512);
  };
  auto compute = [&](const u16* asb, const u16* bsb) {
    bf16x8 af[4], bfr[4];
    #pragma unroll
    for (int ti = 0; ti < 4; ++ti)
      af[ti] = *(const bf16x8*)&asb[(wr * 64 + ti * 16 + fr) * 32 + fq];
    #pragma unroll
    for (int tj = 0; tj < 4; ++tj)
      bfr[tj] = *(const bf16x8*)&bsb[(wc * 64 + tj * 16 + fr) * 32 + fq];
    #pragma unroll
    for (int ti = 0; ti < 4; ++ti)
      #pragma unroll
      for (int tj = 0; tj < 4; ++tj)
        acc[ti][tj] = __builtin_amdgcn_mfma_f32_16x16x32_bf16(af[ti], bfr[tj], acc[ti][tj], 0, 0, 0);
  };

  // buffer ring pointers (named, rotated by assignment — stays in registers)
  u16 *A0 = &As[0][0], *A1 = &As[1][0], *A2 = &As[2][0], *A3 = &As[3][0];
  u16 *B0 = &Bs[0][0], *B1 = &Bs[1][0], *B2 = &Bs[2][0], *B3 = &Bs[3][0];

  // prologue: tiles 0,1,2 in flight (12 outstanding vmem ops/wave)
  stageTo(0,  A0, B0);
  stageTo(32, A1, B1);
  stageTo(64, A2, B2);

  for (int kt = 0; kt < nsteps; ++kt) {
    const int rem = nsteps - 1 - kt;   // tiles staged beyond kt: min(rem,2)
    if (rem >= 2)      asm volatile("s_waitcnt vmcnt(8) lgkmcnt(0)" ::: "memory");
    else if (rem == 1) asm volatile("s_waitcnt vmcnt(4) lgkmcnt(0)" ::: "memory");
    else               asm volatile("s_waitcnt vmcnt(0) lgkmcnt(0)" ::: "memory");
    __builtin_amdgcn_s_barrier();      // raw barrier: no vmcnt drain
    if (kt + 3 < nsteps) stageTo((kt + 3) * 32, A3, B3);  // A3/B3: computed at kt-1
    compute(A0, B0);
    // rotate ring: (A0,A1,A2,A3) <- (A1,A2,A3,A0)
    u16* ta = A0; A0 = A1; A1 = A2; A2 = A3; A3 = ta;
    u16* tb = B0; B0 = B1; B1 = B2; B2 = B3; B3 = tb;
  }

  float* Cf = (float*)Cv + (size_t)kz * ((size_t)M * N);
  u16*  Cb = (u16*)Cv;
  const float* Xf = (const float*)Xv;
  const u16*  Xb = (const u16*)Xv;
  const int rbase = (lane >> 4) * 4;
  const int cofs  = lane & 15;
  #pragma unroll
  for (int ti = 0; ti < 4; ++ti) {
    #pragma unroll
    for (int r = 0; r < 4; ++r) {
      const int gr = row0 + wr * 64 + ti * 16 + rbase + r;
      #pragma unroll
      for (int tj = 0; tj < 4; ++tj) {
        const int gc = col0 + wc * 64 + tj * 16 + cofs;
        const size_t off = (size_t)gr * N + gc;
        const float v = acc[ti][tj][r];
        if constexpr (MODE == 0) {
          Cf[off] = v;
        } else if constexpr (MODE == 1) {
          Cf[off] = v + Xf[off];
        } else if constexpr (MODE == 2) {
          Cb[off] = f2b(v);
        } else {
          const float g = b2f(Xb[off]);
          Cb[off] = f2b((g / (1.f + __expf(-g))) * v);
        }
      }
    }
  }
}

// ---------------------------------------------------------------------------
// Kernel 4b: split-K partial reduce. out = sum_{z<NP} p[z*nper + i] (+ resid).
// Memory-bound; float4 lanes. resid==nullptr skips the residual (uniform).
// ---------------------------------------------------------------------------
template <int NP>
__global__ __launch_bounds__(256) void reduce_kernel(
    const float* __restrict__ p, const float* __restrict__ resid,
    float* __restrict__ out, size_t nper)
{
  const size_t i = ((size_t)blockIdx.x * 256 + threadIdx.x) * 4;
  float4 s = *(const float4*)&p[i];
  #pragma unroll
  for (int z = 1; z < NP; ++z) {
    const float4 a = *(const float4*)&p[(size_t)z * nper + i];
    s.x += a.x; s.y += a.y; s.z += a.z; s.w += a.w;
  }
  if (resid) {
    const float4 r = *(const float4*)&resid[i];
    s.x += r.x; s.y += r.y; s.z += r.z; s.w += r.w;
  }
  *(float4*)&out[i] = s;
}

// ---------------------------------------------------------------------------
// Kernel 5: RoPE in-place on fused qkv f32 buffer [M][3072]
// q: cols h*64 (h<32); k: cols 2048 + kh*64 (kh<8). pair (i, i+32).
// ---------------------------------------------------------------------------
__global__ __launch_bounds__(256) void rope_kernel(
    float* __restrict__ qkv, const int* __restrict__ pid)
{
  const int idx = blockIdx.x * 256 + threadIdx.x;
  const int total = M_ * (NH_ + NKV_) * 32;   // 2,621,440
  if (idx >= total) return;
  const int row = idx / 1280;
  const int rem = idx - row * 1280;
  const int head = rem >> 5;
  const int i = rem & 31;
  const int col = (head < NH_) ? head * 64 : 2048 + (head - NH_) * 64;
  float* base = qkv + (size_t)row * 3072 + col;
  const int pos = pid[row] + LCK_;
  // 10000^(-i/32) = exp2(-i * log2(10000)/32); v_exp_f32 path, no libm powf
  const float invf = exp2f((float)i * (-13.2877123795494f / 32.0f));
  const float ang = (float)pos * invf;
  float sn, c;
  __sincosf(ang, &sn, &c);
  const float x0 = base[i];
  const float x1 = base[i + 32];
  base[i]      = x0 * c - x1 * sn;
  base[i + 32] = x1 * c + x0 * sn;
}

// ---------------------------------------------------------------------------
// Kernel 6: MFMA flash attention. Block = (b,h,qt): 64 q rows, 4 waves x 16.
// QK^T and PV via mfma_f32_16x16x32_bf16; K/V staged bf16 in LDS (V transposed),
// P round-trips LDS in A-layout. Rows padded to 72 u16 (144B: 16B-aligned,
// bank-rotated). Online softmax per wave. 3 diagonal extras merged at end.
// ---------------------------------------------------------------------------
__global__ __launch_bounds__(256) void attn_kernel(
    const float* __restrict__ qkv,
    const float* __restrict__ ck, const float* __restrict__ cv,
    u16* __restrict__ ao)
{
  const int bid = blockIdx.x;
  const int qt = bid & 15;
  const int bh = bid >> 4;
  const int h = bh & 31;
  const int b = bh >> 5;
  const int t = threadIdx.x;
  const int lane = t & 63;
  const int w = t >> 6;
  const int qbase = qt * 64;

  const int fr = lane & 15;            // A-frag m / B-frag n
  const int fq = (lane >> 4) * 8;      // frag k base
  const int rbase = (lane >> 4) * 4;   // C-layout row base
  const int cofs = lane & 15;          // C-layout col

  __shared__ __align__(16) u16 Qs[64 * 72];    // [qrow][d], pre-scaled bf16
  __shared__ __align__(16) u16 Ks[64 * 72];    // [key][d]
  __shared__ __align__(16) u16 Vts[64 * 72];   // [d][key]
  __shared__ __align__(16) u16 Ps[64 * 72];    // [qrow][key] per-wave slices
  __shared__ float Ls[192];

  const size_t bh_off = (size_t)b * NH_ + h;
  const float* K0 = ck + bh_off * S_ * D_;
  const float* V0 = cv + bh_off * S_ * D_;

  // stage Q once: thread t -> row sr = t>>2, d-chunk sc = (t&3)*16
  const int sr = t >> 2;
  const int sc = (t & 3) * 16;
  {
    const float* qg = qkv + (size_t)(b * S_ + qbase + sr) * 3072 + h * 64 + sc;
    float4 a = *(const float4*)&qg[0], bb = *(const float4*)&qg[4],
           c = *(const float4*)&qg[8], d = *(const float4*)&qg[12];
    a.x*=0.125f; a.y*=0.125f; a.z*=0.125f; a.w*=0.125f;
    bb.x*=0.125f; bb.y*=0.125f; bb.z*=0.125f; bb.w*=0.125f;
    c.x*=0.125f; c.y*=0.125f; c.z*=0.125f; c.w*=0.125f;
    d.x*=0.125f; d.y*=0.125f; d.z*=0.125f; d.w*=0.125f;
    bf16x8 lo, hi; cvt16(a, bb, c, d, lo, hi);
    *(bf16x8*)&Qs[sr * 72 + sc] = lo;
    *(bf16x8*)&Qs[sr * 72 + sc + 8] = hi;
  }

  float m_r[4], l_r[4];
  f32x4 Oacc[4];
  #pragma unroll
  for (int r = 0; r < 4; ++r) { m_r[r] = -3.0e38f; l_r[r] = 0.f; }
  #pragma unroll
  for (int dt = 0; dt < 4; ++dt)
    #pragma unroll
    for (int r = 0; r < 4; ++r) Oacc[dt][r] = 0.f;

  for (int kt = 0; kt <= qt; ++kt) {
    __syncthreads();   // prior QK/PV reads of Ks/Vts done
    {
      const float* kg = K0 + (size_t)(kt * 64 + sr) * D_ + sc;
      float4 a = *(const float4*)&kg[0], bb = *(const float4*)&kg[4],
             c = *(const float4*)&kg[8], d = *(const float4*)&kg[12];
      bf16x8 lo, hi; cvt16(a, bb, c, d, lo, hi);
      *(bf16x8*)&Ks[sr * 72 + sc] = lo;
      *(bf16x8*)&Ks[sr * 72 + sc + 8] = hi;
      const float* vg = V0 + (size_t)(kt * 64 + sr) * D_ + sc;
      float4 va = *(const float4*)&vg[0], vb4 = *(const float4*)&vg[4],
             vc = *(const float4*)&vg[8], vd = *(const float4*)&vg[12];
      const float vv[16] = {va.x,va.y,va.z,va.w, vb4.x,vb4.y,vb4.z,vb4.w,
                            vc.x,vc.y,vc.z,vc.w, vd.x,vd.y,vd.z,vd.w};
      #pragma unroll
      for (int i = 0; i < 16; ++i) Vts[(sc + i) * 72 + sr] = f2b(vv[i]);
    }
    __syncthreads();   // staged tiles visible

    // ---- QK^T: wave w computes S[16 rows][64 keys] ----
    const bf16x8 qa0 = *(const bf16x8*)&Qs[(w * 16 + fr) * 72 + fq];
    const bf16x8 qa1 = *(const bf16x8*)&Qs[(w * 16 + fr) * 72 + 32 + fq];
    f32x4 sacc[4];
    #pragma unroll
    for (int nt = 0; nt < 4; ++nt) {
      const bf16x8 kb0 = *(const bf16x8*)&Ks[(nt * 16 + fr) * 72 + fq];
      const bf16x8 kb1 = *(const bf16x8*)&Ks[(nt * 16 + fr) * 72 + 32 + fq];
      f32x4 z; z[0]=0.f; z[1]=0.f; z[2]=0.f; z[3]=0.f;
      z = __builtin_amdgcn_mfma_f32_16x16x32_bf16(qa0, kb0, z, 0, 0, 0);
      sacc[nt] = __builtin_amdgcn_mfma_f32_16x16x32_bf16(qa1, kb1, z, 0, 0, 0);
    }
    if (kt == qt) {   // causal mask inside diagonal tile
      #pragma unroll
      for (int nt = 0; nt < 4; ++nt) {
        const int key = nt * 16 + cofs;
        #pragma unroll
        for (int r = 0; r < 4; ++r)
          if (key > w * 16 + rbase + r) sacc[nt][r] = -3.0e38f;
      }
    }

    // ---- online softmax (per wave, rows rbase..rbase+3 of wave's 16) ----
    #pragma unroll
    for (int r = 0; r < 4; ++r) {
      float rm = fmaxf(fmaxf(sacc[0][r], sacc[1][r]), fmaxf(sacc[2][r], sacc[3][r]));
      rm = fmaxf(rm, __shfl_xor(rm, 1));
      rm = fmaxf(rm, __shfl_xor(rm, 2));
      rm = fmaxf(rm, __shfl_xor(rm, 4));
      rm = fmaxf(rm, __shfl_xor(rm, 8));
      const float mnew = fmaxf(m_r[r], rm);
      const float alpha = __expf(m_r[r] - mnew);
      float p0 = __expf(sacc[0][r] - mnew);
      float p1 = __expf(sacc[1][r] - mnew);
      float p2 = __expf(sacc[2][r] - mnew);
      float p3 = __expf(sacc[3][r] - mnew);
      float rs = p0 + p1 + p2 + p3;
      rs += __shfl_xor(rs, 1);
      rs += __shfl_xor(rs, 2);
      rs += __shfl_xor(rs, 4);
      rs += __shfl_xor(rs, 8);
      l_r[r] = l_r[r] * alpha + rs;
      m_r[r] = mnew;
      #pragma unroll
      for (int dt = 0; dt < 4; ++dt) Oacc[dt][r] *= alpha;
      u16* prow = &Ps[(w * 16 + rbase + r) * 72 + cofs];
      prow[0]  = f2b(p0);
      prow[16] = f2b(p1);
      prow[32] = f2b(p2);
      prow[48] = f2b(p3);
    }

    // ---- PV: O[16 rows][64 d] += P @ V (wave-local P, block Vts) ----
    const bf16x8 pa0 = *(const bf16x8*)&Ps[(w * 16 + fr) * 72 + fq];
    const bf16x8 pa1 = *(const bf16x8*)&Ps[(w * 16 + fr) * 72 + 32 + fq];
    #pragma unroll
    for (int dt = 0; dt < 4; ++dt) {
      const bf16x8 vb0 = *(const bf16x8*)&Vts[(dt * 16 + fr) * 72 + fq];
      const bf16x8 vb1 = *(const bf16x8*)&Vts[(dt * 16 + fr) * 72 + 32 + fq];
      Oacc[dt] = __builtin_amdgcn_mfma_f32_16x16x32_bf16(pa0, vb0, Oacc[dt], 0, 0, 0);
      Oacc[dt] = __builtin_amdgcn_mfma_f32_16x16x32_bf16(pa1, vb1, Oacc[dt], 0, 0, 0);
    }
  }

  // ---- 3 diagonal extras: logits ----
  if (t < 192) {
    const int n = t >> 6;
    const int r = t & 63;
    const int qp = qbase + r;
    const float* kp;
    if (n < 2) kp = ck + ((((size_t)(n + 1) * B_ + b) * NH_ + h) * S_ + qp) * D_;
    else       kp = qkv + (size_t)(b * S_ + qp) * 3072 + 2048 + (h >> 2) * 64;
    float e = 0.f;
    #pragma unroll 16
    for (int d = 0; d < 64; ++d) e = fmaf(b2f(Qs[r * 72 + d]), kp[d], e);
    Ls[n * 64 + r] = e;
  }
  __syncthreads();

  // ---- merge extras + normalize + store bf16 ----
  #pragma unroll
  for (int r = 0; r < 4; ++r) {
    const int qr = w * 16 + rbase + r;
    const int qp = qbase + qr;
    const float e0 = Ls[qr], e1 = Ls[64 + qr], e2 = Ls[128 + qr];
    const float mnew = fmaxf(fmaxf(m_r[r], e0), fmaxf(e1, e2));
    const float alpha = __expf(m_r[r] - mnew);
    const float p0 = __expf(e0 - mnew);
    const float p1 = __expf(e1 - mnew);
    const float p2 = __expf(e2 - mnew);
    const float inv = 1.0f / (l_r[r] * alpha + p0 + p1 + p2);
    const float* v1p = cv + ((((size_t)1 * B_ + b) * NH_ + h) * S_ + qp) * D_;
    const float* v2p = cv + ((((size_t)2 * B_ + b) * NH_ + h) * S_ + qp) * D_;
    const float* v3p = qkv + (size_t)(b * S_ + qp) * 3072 + 2560 + (h >> 2) * 64;
    u16* aorow = ao + (size_t)(b * S_ + qp) * 2048 + h * 64;
    #pragma unroll
    for (int dt = 0; dt < 4; ++dt) {
      const int col = dt * 16 + cofs;
      const float o = (Oacc[dt][r] * alpha + p0 * v1p[col] + p1 * v2p[col] + p2 * v3p[col]) * inv;
      aorow[col] = f2b(o);
    }
  }
}

// ---------------------------------------------------------------------------
extern "C" void kernel_launch(void* const* d_in, const int* in_sizes, int n_in,
                              void* d_out, int out_size, void* d_ws, size_t ws_size,
                              hipStream_t stream)
{
  const float* input_emb = (const float*)d_in[0];
  const float* hidden    = (const float*)d_in[1];
  const float* cache_k   = (const float*)d_in[2];
  const float* cache_v   = (const float*)d_in[3];
  const int*   pos_ids   = (const int*)d_in[5];
  const float* wq = (const float*)d_in[6];
  const float* wk = (const float*)d_in[7];
  const float* wv = (const float*)d_in[8];
  const float* wo = (const float*)d_in[9];
  const float* wg = (const float*)d_in[10];
  const float* wu = (const float*)d_in[11];
  const float* wd = (const float*)d_in[12];
  const float* w_hidden_norm = (const float*)d_in[13];
  const float* w_input_ln    = (const float*)d_in[14];
  const float* w_post_ln     = (const float*)d_in[15];
  float* out = (float*)d_out;

  // Workspace (bytes), peak 167.8 MiB, lifetime-aliased:
  //  [0,25.2M)      wqkv_b (wq|wk|wv packed rows = 3072x4096)  -> dead after qkv GEMM
  //  [25.2,33.6M)   wo_b   -> dead after wo GEMM
  //  [33.6,67.1M)   wg_b   -> dead after gate GEMM; then wd_b
  //  [67.1,100.7M)  wu_b   -> dead after up GEMM; then down split-K partials (67M)
  //  [100.7,117.4M) x_b    -> dead after qkv GEMM; then wo partials; then hn
  //  [117.4,142.6M) qkvf f32 [M][3072] -> dead after attn; then gbb (33.5M)
  //  [142.6,151M)   qkv partial z=1 head; then ao bf16 -> dead after wo GEMM
  //  [151,167.8M)   qkv partial z=1 tail; then h2 f32 -> live to end
  char* wsb = (char*)d_ws;
  u16*   wall   = (u16*)(wsb + 0);
  u16*   wqkv_b = wall;
  u16*   wo_b   = (u16*)(wsb + 25165824);
  u16*   wg_b   = (u16*)(wsb + 33554432);
  u16*   wu_b   = (u16*)(wsb + 67108864);
  u16*   xb     = (u16*)(wsb + 100663296);
  float* qkvf   = (float*)(wsb + 117440512);
  u16*   ao     = (u16*)(wsb + 142606336);
  float* h2     = (float*)(wsb + 150994944);
  u16*   hn     = (u16*)(wsb + 100663296);   // alias x_b
  u16*   gbb    = (u16*)(wsb + 117440512);   // alias qkvf+ao
  u16*   gub    = (u16*)(wsb + 0);           // alias wqkv_b+wo_b
  u16*   wd_b   = (u16*)(wsb + 33554432);    // alias wg_b
  float* wo_p   = (float*)(wsb + 100663296); // wo split-K partials (2x16.8M, dead xb+qkvf)
  float* dn_p   = (float*)(wsb + 67108864);  // down split-K partials (4x16.8M, dead wu_b..gbb)

  // 1. weights -> bf16
  convert6_kernel<<<24576, 256, 0, stream>>>(wq, wk, wv, wo, wg, wu, wall);
  // 2. fused norms + concat -> bf16 x
  norm_concat_kernel<<<M_, 256, 0, stream>>>(input_emb, hidden, w_input_ln, w_hidden_norm, xb);
  // 3. fused QKV projection (N=3072), split-K=2 -> partials at qkvf (+M*N), reduce in place
  gemm_bf16_kernel<0><<<dim3(24, 16, 2), 256, 0, stream>>>(xb, wqkv_b, qkvf, nullptr, M_, 3072, 4096);
  reduce_kernel<2><<<6144, 256, 0, stream>>>(qkvf, nullptr, qkvf, (size_t)M_ * 3072);
  // 4. RoPE in-place on qkvf
  rope_kernel<<<10240, 256, 0, stream>>>(qkvf, pos_ids);
  // 5. MFMA flash attention -> bf16 ao
  attn_kernel<<<B_ * NH_ * (S_ / 64), 256, 0, stream>>>(qkvf, cache_k, cache_v, ao);
  // 6. output projection split-K=2 -> partials; reduce + residual(hidden) -> f32 h2
  gemm_bf16_kernel<0><<<dim3(16, 16, 2), 256, 0, stream>>>(ao, wo_b, wo_p, nullptr, M_, 2048, 2048);
  reduce_kernel<2><<<4096, 256, 0, stream>>>(wo_p, hidden, h2, (size_t)M_ * 2048);
  // 7. post-attention RMSNorm -> bf16 hn
  rmsnorm_kernel<<<M_, 256, 0, stream>>>(h2, w_post_ln, hn);
  // 8. gate GEMM -> bf16 gbb
  gemm_bf16_kernel<2><<<dim3(64, 16), 256, 0, stream>>>(hn, wg_b, gbb, nullptr, M_, 8192, 2048);
  // 9. wd -> bf16 (wg_b region now dead)
  convert1_kernel<<<8192, 256, 0, stream>>>(wd, wd_b);
  // 10. up GEMM, epilogue silu(gate)*up -> bf16 gub
  gemm_bf16_kernel<3><<<dim3(64, 16), 256, 0, stream>>>(hn, wu_b, gub, gbb, M_, 8192, 2048);
  // 11. down GEMM split-K=4 -> partials; reduce + residual(h2) -> out f32
  gemm_bf16_kernel<0><<<dim3(16, 16, 4), 256, 0, stream>>>(gub, wd_b, dn_p, nullptr, M_, 2048, 8192);
  reduce_kernel<4><<<4096, 256, 0, stream>>>(dn_p, h2, out, (size_t)M_ * 2048);
}

// Round 4
// 824.950 us; speedup vs baseline: 1.2737x; 1.0651x over previous
//
#include <hip/hip_runtime.h>
#include <math.h>

#define B_   2
#define S_   1024
#define H_   2048
#define NH_  32
#define NKV_ 8
#define D_   64
#define I_   8192
#define LCK_ 3
#define M_   (B_ * S_)   // 2048 token rows

typedef unsigned short u16;
typedef unsigned int   u32;
typedef __attribute__((ext_vector_type(8))) short bf16x8;   // 8 bf16 (4 VGPRs)
typedef __attribute__((ext_vector_type(4))) float f32x4;
typedef __attribute__((ext_vector_type(2))) unsigned int u32x2;

// f32 -> bf16 round-to-nearest-even (finite inputs)
__device__ __forceinline__ u16 f2b(float f) {
  u32 u = __float_as_uint(f);
  u += 0x7fffu + ((u >> 16) & 1u);
  return (u16)(u >> 16);
}
__device__ __forceinline__ float b2f(u16 h) { return __uint_as_float(((u32)h) << 16); }

__device__ __forceinline__ void st_bf4(u16* p, float a, float b, float c, float d) {
  u32x2 v;
  v.x = (u32)f2b(a) | ((u32)f2b(b) << 16);
  v.y = (u32)f2b(c) | ((u32)f2b(d) << 16);
  *(u32x2*)p = v;
}

// pack 4 f32x4 -> two bf16x8
__device__ __forceinline__ void cvt16(const float4& a, const float4& b,
                                      const float4& c, const float4& d,
                                      bf16x8& lo, bf16x8& hi) {
  lo[0] = (short)f2b(a.x); lo[1] = (short)f2b(a.y); lo[2] = (short)f2b(a.z); lo[3] = (short)f2b(a.w);
  lo[4] = (short)f2b(b.x); lo[5] = (short)f2b(b.y); lo[6] = (short)f2b(b.z); lo[7] = (short)f2b(b.w);
  hi[0] = (short)f2b(c.x); hi[1] = (short)f2b(c.y); hi[2] = (short)f2b(c.z); hi[3] = (short)f2b(c.w);
  hi[4] = (short)f2b(d.x); hi[5] = (short)f2b(d.y); hi[6] = (short)f2b(d.z); hi[7] = (short)f2b(d.w);
}

// async global->LDS, 16B per lane; LDS dest = wave-uniform base + lane*16
__device__ __forceinline__ void async16(const void* g, void* l) {
  __builtin_amdgcn_global_load_lds(
      (const __attribute__((address_space(1))) unsigned int*)(uintptr_t)g,
      (__attribute__((address_space(3))) unsigned int*)(unsigned int)(uintptr_t)l,
      16, 0, 0);
}

// ---------------------------------------------------------------------------
// Kernel 1: fused RMSNorm(emb)+RMSNorm(hidden) -> x = concat([e,h]) as BF16
// ---------------------------------------------------------------------------
__global__ __launch_bounds__(256) void norm_concat_kernel(
    const float* __restrict__ emb, const float* __restrict__ hid,
    const float* __restrict__ w_e, const float* __restrict__ w_h,
    u16* __restrict__ x)
{
  const int row = blockIdx.x;
  const int t = threadIdx.x;
  const float* e = emb + (size_t)row * H_;
  const float* h = hid + (size_t)row * H_;

  const float4 ev0 = *(const float4*)&e[t * 4];
  const float4 ev1 = *(const float4*)&e[t * 4 + 1024];
  const float4 hv0 = *(const float4*)&h[t * 4];
  const float4 hv1 = *(const float4*)&h[t * 4 + 1024];

  float se = ev0.x*ev0.x + ev0.y*ev0.y + ev0.z*ev0.z + ev0.w*ev0.w
           + ev1.x*ev1.x + ev1.y*ev1.y + ev1.z*ev1.z + ev1.w*ev1.w;
  float sh = hv0.x*hv0.x + hv0.y*hv0.y + hv0.z*hv0.z + hv0.w*hv0.w
           + hv1.x*hv1.x + hv1.y*hv1.y + hv1.z*hv1.z + hv1.w*hv1.w;

  #pragma unroll
  for (int m = 1; m < 64; m <<= 1) {
    se += __shfl_xor(se, m);
    sh += __shfl_xor(sh, m);
  }
  __shared__ float red[8];
  const int wv = t >> 6;
  if ((t & 63) == 0) { red[wv] = se; red[4 + wv] = sh; }
  __syncthreads();
  se = red[0] + red[1] + red[2] + red[3];
  sh = red[4] + red[5] + red[6] + red[7];

  const float re = 1.0f / sqrtf(se * (1.0f / H_) + 1e-6f);
  const float rh = 1.0f / sqrtf(sh * (1.0f / H_) + 1e-6f);

  const float4 we0 = *(const float4*)&w_e[t * 4];
  const float4 we1 = *(const float4*)&w_e[t * 4 + 1024];
  const float4 wh0 = *(const float4*)&w_h[t * 4];
  const float4 wh1 = *(const float4*)&w_h[t * 4 + 1024];

  u16* xr = x + (size_t)row * (2 * H_);
  st_bf4(&xr[t * 4],        ev0.x*re*we0.x, ev0.y*re*we0.y, ev0.z*re*we0.z, ev0.w*re*we0.w);
  st_bf4(&xr[t * 4 + 1024], ev1.x*re*we1.x, ev1.y*re*we1.y, ev1.z*re*we1.z, ev1.w*re*we1.w);
  st_bf4(&xr[2048 + t * 4],        hv0.x*rh*wh0.x, hv0.y*rh*wh0.y, hv0.z*rh*wh0.z, hv0.w*rh*wh0.w);
  st_bf4(&xr[2048 + t * 4 + 1024], hv1.x*rh*wh1.x, hv1.y*rh*wh1.y, hv1.z*rh*wh1.z, hv1.w*rh*wh1.w);
}

// ---------------------------------------------------------------------------
// Kernel 2: RMSNorm f32 in -> BF16 out (post-attention norm)
// ---------------------------------------------------------------------------
__global__ __launch_bounds__(256) void rmsnorm_kernel(
    const float* __restrict__ in, const float* __restrict__ w, u16* __restrict__ outp)
{
  const int row = blockIdx.x;
  const int t = threadIdx.x;
  const float* p = in + (size_t)row * H_;
  const float4 v0 = *(const float4*)&p[t * 4];
  const float4 v1 = *(const float4*)&p[t * 4 + 1024];
  float s = v0.x*v0.x + v0.y*v0.y + v0.z*v0.z + v0.w*v0.w
          + v1.x*v1.x + v1.y*v1.y + v1.z*v1.z + v1.w*v1.w;
  #pragma unroll
  for (int m = 1; m < 64; m <<= 1) s += __shfl_xor(s, m);
  __shared__ float red[4];
  const int wv = t >> 6;
  if ((t & 63) == 0) red[wv] = s;
  __syncthreads();
  s = red[0] + red[1] + red[2] + red[3];
  const float rs = 1.0f / sqrtf(s * (1.0f / H_) + 1e-6f);

  const float4 w0 = *(const float4*)&w[t * 4];
  const float4 w1 = *(const float4*)&w[t * 4 + 1024];
  u16* orow = outp + (size_t)row * H_;
  st_bf4(&orow[t * 4],        v0.x*rs*w0.x, v0.y*rs*w0.y, v0.z*rs*w0.z, v0.w*rs*w0.w);
  st_bf4(&orow[t * 4 + 1024], v1.x*rs*w1.x, v1.y*rs*w1.y, v1.z*rs*w1.z, v1.w*rs*w1.w);
}

// ---------------------------------------------------------------------------
// Kernel 3: weight f32->bf16 converters
// convert6: wq|wk|wv|wo|wg|wu packed contiguously into dst (element order)
// ---------------------------------------------------------------------------
__global__ __launch_bounds__(256) void convert6_kernel(
    const float* __restrict__ wq, const float* __restrict__ wk, const float* __restrict__ wv,
    const float* __restrict__ wo, const float* __restrict__ wg, const float* __restrict__ wu,
    u16* __restrict__ dst)
{
  const size_t i8 = ((size_t)blockIdx.x * 256 + threadIdx.x) * 8;
  const float* s; size_t base;
  if      (i8 <  8388608) { s = wq; base = 0; }
  else if (i8 < 10485760) { s = wk; base = 8388608; }
  else if (i8 < 12582912) { s = wv; base = 10485760; }
  else if (i8 < 16777216) { s = wo; base = 12582912; }
  else if (i8 < 33554432) { s = wg; base = 16777216; }
  else                    { s = wu; base = 33554432; }
  const float4 a = *(const float4*)&s[i8 - base];
  const float4 b = *(const float4*)&s[i8 - base + 4];
  bf16x8 r;
  r[0] = (short)f2b(a.x); r[1] = (short)f2b(a.y); r[2] = (short)f2b(a.z); r[3] = (short)f2b(a.w);
  r[4] = (short)f2b(b.x); r[5] = (short)f2b(b.y); r[6] = (short)f2b(b.z); r[7] = (short)f2b(b.w);
  *(bf16x8*)&dst[i8] = r;
}

__global__ __launch_bounds__(256) void convert1_kernel(
    const float* __restrict__ src, u16* __restrict__ dst)
{
  const size_t i8 = ((size_t)blockIdx.x * 256 + threadIdx.x) * 8;
  const float4 a = *(const float4*)&src[i8];
  const float4 b = *(const float4*)&src[i8 + 4];
  bf16x8 r;
  r[0] = (short)f2b(a.x); r[1] = (short)f2b(a.y); r[2] = (short)f2b(a.z); r[3] = (short)f2b(a.w);
  r[4] = (short)f2b(b.x); r[5] = (short)f2b(b.y); r[6] = (short)f2b(b.z); r[7] = (short)f2b(b.w);
  *(bf16x8*)&dst[i8] = r;
}

// ---------------------------------------------------------------------------
// Kernel 4: BF16 MFMA NT-GEMM, 128x128 tile, depth-3 counted-vmcnt pipeline.
// (kept for wo: small-N grids need the 128^2 tiling for occupancy)
// ---------------------------------------------------------------------------
template <int MODE>
__global__ __launch_bounds__(256) void gemm_bf16_kernel(
    const u16* __restrict__ A, const u16* __restrict__ Bw,
    void* Cv, const void* Xv, int M, int N, int K)
{
  __shared__ __align__(16) u16 As[4][128 * 32];   // 4 x 8 KB
  __shared__ __align__(16) u16 Bs[4][128 * 32];   // 4 x 8 KB  (64 KB total)
  const int t = threadIdx.x;
  const int lane = t & 63;
  const int w = t >> 6;
  const int wr = w >> 1, wc = w & 1;
  const int row0 = blockIdx.y * 128;
  const int col0 = blockIdx.x * 128;
  const int kz = blockIdx.z;
  const int Kc = K / (int)gridDim.z;   // per-slice K extent (stride stays K)
  const int nsteps = Kc >> 5;          // BK=32 tiles

  f32x4 acc[4][4];
  #pragma unroll
  for (int i = 0; i < 4; ++i)
    #pragma unroll
    for (int j = 0; j < 4; ++j)
      #pragma unroll
      for (int r = 0; r < 4; ++r) acc[i][j][r] = 0.f;

  const int srow = lane >> 2;
  const int skc  = (lane & 3) * 8;
  const u16* Ag = A  + (size_t)(row0 + w * 32 + srow) * K + skc + (size_t)kz * Kc;
  const u16* Bg = Bw + (size_t)(col0 + w * 32 + srow) * K + skc + (size_t)kz * Kc;
  const int wofs = w * 1024;           // per-wave 32x32 region within a buffer

  const int fr = lane & 15;
  const int fq = (lane >> 4) * 8;

  auto stageTo = [&](int k0, u16* ab, u16* bb) {
    async16(Ag + k0,                  ab + wofs);
    async16(Ag + k0 + (size_t)16 * K, ab + wofs + 512);
    async16(Bg + k0,                  bb + wofs);
    async16(Bg + k0 + (size_t)16 * K, bb + wofs + 512);
  };
  auto compute = [&](const u16* asb, const u16* bsb) {
    bf16x8 af[4], bfr[4];
    #pragma unroll
    for (int ti = 0; ti < 4; ++ti)
      af[ti] = *(const bf16x8*)&asb[(wr * 64 + ti * 16 + fr) * 32 + fq];
    #pragma unroll
    for (int tj = 0; tj < 4; ++tj)
      bfr[tj] = *(const bf16x8*)&bsb[(wc * 64 + tj * 16 + fr) * 32 + fq];
    #pragma unroll
    for (int ti = 0; ti < 4; ++ti)
      #pragma unroll
      for (int tj = 0; tj < 4; ++tj)
        acc[ti][tj] = __builtin_amdgcn_mfma_f32_16x16x32_bf16(af[ti], bfr[tj], acc[ti][tj], 0, 0, 0);
  };

  u16 *A0 = &As[0][0], *A1 = &As[1][0], *A2 = &As[2][0], *A3 = &As[3][0];
  u16 *B0 = &Bs[0][0], *B1 = &Bs[1][0], *B2 = &Bs[2][0], *B3 = &Bs[3][0];

  stageTo(0,  A0, B0);
  stageTo(32, A1, B1);
  stageTo(64, A2, B2);

  for (int kt = 0; kt < nsteps; ++kt) {
    const int rem = nsteps - 1 - kt;
    if (rem >= 2)      asm volatile("s_waitcnt vmcnt(8) lgkmcnt(0)" ::: "memory");
    else if (rem == 1) asm volatile("s_waitcnt vmcnt(4) lgkmcnt(0)" ::: "memory");
    else               asm volatile("s_waitcnt vmcnt(0) lgkmcnt(0)" ::: "memory");
    __builtin_amdgcn_s_barrier();      // raw barrier: no vmcnt drain
    if (kt + 3 < nsteps) stageTo((kt + 3) * 32, A3, B3);
    compute(A0, B0);
    u16* ta = A0; A0 = A1; A1 = A2; A2 = A3; A3 = ta;
    u16* tb = B0; B0 = B1; B1 = B2; B2 = B3; B3 = tb;
  }

  float* Cf = (float*)Cv + (size_t)kz * ((size_t)M * N);
  u16*  Cb = (u16*)Cv;
  const float* Xf = (const float*)Xv;
  const u16*  Xb = (const u16*)Xv;
  const int rbase = (lane >> 4) * 4;
  const int cofs  = lane & 15;
  #pragma unroll
  for (int ti = 0; ti < 4; ++ti) {
    #pragma unroll
    for (int r = 0; r < 4; ++r) {
      const int gr = row0 + wr * 64 + ti * 16 + rbase + r;
      #pragma unroll
      for (int tj = 0; tj < 4; ++tj) {
        const int gc = col0 + wc * 64 + tj * 16 + cofs;
        const size_t off = (size_t)gr * N + gc;
        const float v = acc[ti][tj][r];
        if constexpr (MODE == 0) {
          Cf[off] = v;
        } else if constexpr (MODE == 1) {
          Cf[off] = v + Xf[off];
        } else if constexpr (MODE == 2) {
          Cb[off] = f2b(v);
        } else {
          const float g = b2f(Xb[off]);
          Cb[off] = f2b((g / (1.f + __expf(-g))) * v);
        }
      }
    }
  }
}

// ---------------------------------------------------------------------------
// Kernel 4c: 256x256 tile, 512 thr (8 waves 2Mx4N), wave = 128x64 output.
// BK=32 (rows stay 64B stride -> bank-balanced, no swizzle needed).
// Depth-3 counted-vmcnt ring over 4 LDS buffer pairs (128 KB, 1 block/CU).
// Per K-step: counted vmcnt + raw barrier, then 4 sub-phases, each
// {2 A-frag ds_reads | 1 stage async16 of tile t+3 | setprio(1) 8 MFMA
//  setprio(0) | barrier} (B-frags read once in phase 0).
// Arithmetic intensity 42.7 FLOP/LDS-byte vs 32 for the 128^2 kernel.
// MODE semantics identical to gemm_bf16_kernel.
// ---------------------------------------------------------------------------
#define MM8(AF0, AF1, M0)                                                            \
  acc[M0][0]   = __builtin_amdgcn_mfma_f32_16x16x32_bf16(AF0, b0, acc[M0][0], 0,0,0);   \
  acc[M0][1]   = __builtin_amdgcn_mfma_f32_16x16x32_bf16(AF0, b1, acc[M0][1], 0,0,0);   \
  acc[M0][2]   = __builtin_amdgcn_mfma_f32_16x16x32_bf16(AF0, b2, acc[M0][2], 0,0,0);   \
  acc[M0][3]   = __builtin_amdgcn_mfma_f32_16x16x32_bf16(AF0, b3, acc[M0][3], 0,0,0);   \
  acc[M0+1][0] = __builtin_amdgcn_mfma_f32_16x16x32_bf16(AF1, b0, acc[M0+1][0], 0,0,0); \
  acc[M0+1][1] = __builtin_amdgcn_mfma_f32_16x16x32_bf16(AF1, b1, acc[M0+1][1], 0,0,0); \
  acc[M0+1][2] = __builtin_amdgcn_mfma_f32_16x16x32_bf16(AF1, b2, acc[M0+1][2], 0,0,0); \
  acc[M0+1][3] = __builtin_amdgcn_mfma_f32_16x16x32_bf16(AF1, b3, acc[M0+1][3], 0,0,0);

template <int MODE>
__global__ __launch_bounds__(512, 2) void gemm256_bf16_kernel(
    const u16* __restrict__ A, const u16* __restrict__ Bw,
    void* Cv, const void* Xv, int M, int N, int K)
{
  __shared__ __align__(16) u16 As[4][256 * 32];   // 4 x 16 KB
  __shared__ __align__(16) u16 Bs[4][256 * 32];   // 4 x 16 KB (128 KB total)
  const int t = threadIdx.x;
  const int lane = t & 63;
  const int w = t >> 6;                // 0..7
  const int wr = w >> 2, wc = w & 3;   // 2M x 4N wave grid
  const int row0 = blockIdx.y * 256;
  const int col0 = blockIdx.x * 256;
  const int kz = blockIdx.z;
  const int Kc = K / (int)gridDim.z;
  const int nsteps = Kc >> 5;

  f32x4 acc[8][4];
  #pragma unroll
  for (int i = 0; i < 8; ++i)
    #pragma unroll
    for (int j = 0; j < 4; ++j)
      #pragma unroll
      for (int r = 0; r < 4; ++r) acc[i][j][r] = 0.f;

  const int srow = lane >> 2;
  const int skc  = (lane & 3) * 8;
  const u16* Ag = A  + (size_t)(row0 + w * 32 + srow) * K + skc + (size_t)kz * Kc;
  const u16* Bg = Bw + (size_t)(col0 + w * 32 + srow) * K + skc + (size_t)kz * Kc;
  const int wofs = w * 1024;           // wave's 32 rows x 32 k within a buffer

  const int fr = lane & 15;
  const int fq = (lane >> 4) * 8;

  u16 *A0 = &As[0][0], *A1 = &As[1][0], *A2 = &As[2][0], *A3 = &As[3][0];
  u16 *B0 = &Bs[0][0], *B1 = &Bs[1][0], *B2 = &Bs[2][0], *B3 = &Bs[3][0];

  auto stageAll = [&](int k0, u16* ab, u16* bb) {
    async16(Ag + k0,                  ab + wofs);
    async16(Ag + k0 + (size_t)16 * K, ab + wofs + 512);
    async16(Bg + k0,                  bb + wofs);
    async16(Bg + k0 + (size_t)16 * K, bb + wofs + 512);
  };

  stageAll(0,  A0, B0);
  stageAll(32, A1, B1);
  stageAll(64, A2, B2);

  for (int kt = 0; kt < nsteps; ++kt) {
    const int rem = nsteps - 1 - kt;
    if (rem >= 2)      asm volatile("s_waitcnt vmcnt(8) lgkmcnt(0)" ::: "memory");
    else if (rem == 1) asm volatile("s_waitcnt vmcnt(4) lgkmcnt(0)" ::: "memory");
    else               asm volatile("s_waitcnt vmcnt(0) lgkmcnt(0)" ::: "memory");
    __builtin_amdgcn_s_barrier();      // raw barrier: loads stay in flight
    const bool doStage = (kt + 3 < nsteps);
    const int ks = (kt + 3) * 32;

    // B-fragments: read once per K-step, reused by all 4 phases
    const bf16x8 b0 = *(const bf16x8*)&B0[(wc * 64 +  0 + fr) * 32 + fq];
    const bf16x8 b1 = *(const bf16x8*)&B0[(wc * 64 + 16 + fr) * 32 + fq];
    const bf16x8 b2 = *(const bf16x8*)&B0[(wc * 64 + 32 + fr) * 32 + fq];
    const bf16x8 b3 = *(const bf16x8*)&B0[(wc * 64 + 48 + fr) * 32 + fq];

    { // phase 0: m=0,1 + stage op 0 (A lo rows of tile kt+3)
      const bf16x8 a0 = *(const bf16x8*)&A0[(wr * 128 +  0 + fr) * 32 + fq];
      const bf16x8 a1 = *(const bf16x8*)&A0[(wr * 128 + 16 + fr) * 32 + fq];
      if (doStage) async16(Ag + ks, A3 + wofs);
      __builtin_amdgcn_s_setprio(1);
      MM8(a0, a1, 0)
      __builtin_amdgcn_s_setprio(0);
    }
    __builtin_amdgcn_s_barrier();
    { // phase 1: m=2,3 + stage op 1 (A hi rows)
      const bf16x8 a0 = *(const bf16x8*)&A0[(wr * 128 + 32 + fr) * 32 + fq];
      const bf16x8 a1 = *(const bf16x8*)&A0[(wr * 128 + 48 + fr) * 32 + fq];
      if (doStage) async16(Ag + ks + (size_t)16 * K, A3 + wofs + 512);
      __builtin_amdgcn_s_setprio(1);
      MM8(a0, a1, 2)
      __builtin_amdgcn_s_setprio(0);
    }
    __builtin_amdgcn_s_barrier();
    { // phase 2: m=4,5 + stage op 2 (B lo rows)
      const bf16x8 a0 = *(const bf16x8*)&A0[(wr * 128 + 64 + fr) * 32 + fq];
      const bf16x8 a1 = *(const bf16x8*)&A0[(wr * 128 + 80 + fr) * 32 + fq];
      if (doStage) async16(Bg + ks, B3 + wofs);
      __builtin_amdgcn_s_setprio(1);
      MM8(a0, a1, 4)
      __builtin_amdgcn_s_setprio(0);
    }
    __builtin_amdgcn_s_barrier();
    { // phase 3: m=6,7 + stage op 3 (B hi rows); trailing barrier is next
      // iteration's top barrier.
      const bf16x8 a0 = *(const bf16x8*)&A0[(wr * 128 +  96 + fr) * 32 + fq];
      const bf16x8 a1 = *(const bf16x8*)&A0[(wr * 128 + 112 + fr) * 32 + fq];
      if (doStage) async16(Bg + ks + (size_t)16 * K, B3 + wofs + 512);
      __builtin_amdgcn_s_setprio(1);
      MM8(a0, a1, 6)
      __builtin_amdgcn_s_setprio(0);
    }

    u16* ta = A0; A0 = A1; A1 = A2; A2 = A3; A3 = ta;
    u16* tb = B0; B0 = B1; B1 = B2; B2 = B3; B3 = tb;
  }

  float* Cf = (float*)Cv + (size_t)kz * ((size_t)M * N);
  u16*  Cb = (u16*)Cv;
  const float* Xf = (const float*)Xv;
  const u16*  Xb = (const u16*)Xv;
  const int rbase = (lane >> 4) * 4;
  const int cofs  = lane & 15;
  #pragma unroll
  for (int m = 0; m < 8; ++m) {
    #pragma unroll
    for (int r = 0; r < 4; ++r) {
      const int gr = row0 + wr * 128 + m * 16 + rbase + r;
      #pragma unroll
      for (int n = 0; n < 4; ++n) {
        const int gc = col0 + wc * 64 + n * 16 + cofs;
        const size_t off = (size_t)gr * N + gc;
        const float v = acc[m][n][r];
        if constexpr (MODE == 0) {
          Cf[off] = v;
        } else if constexpr (MODE == 1) {
          Cf[off] = v + Xf[off];
        } else if constexpr (MODE == 2) {
          Cb[off] = f2b(v);
        } else {
          const float g = b2f(Xb[off]);
          Cb[off] = f2b((g / (1.f + __expf(-g))) * v);
        }
      }
    }
  }
}

// ---------------------------------------------------------------------------
// Kernel 4b: split-K partial reduce. out = sum_{z<NP} p[z*nper + i] (+ resid).
// ---------------------------------------------------------------------------
template <int NP>
__global__ __launch_bounds__(256) void reduce_kernel(
    const float* __restrict__ p, const float* __restrict__ resid,
    float* __restrict__ out, size_t nper)
{
  const size_t i = ((size_t)blockIdx.x * 256 + threadIdx.x) * 4;
  float4 s = *(const float4*)&p[i];
  #pragma unroll
  for (int z = 1; z < NP; ++z) {
    const float4 a = *(const float4*)&p[(size_t)z * nper + i];
    s.x += a.x; s.y += a.y; s.z += a.z; s.w += a.w;
  }
  if (resid) {
    const float4 r = *(const float4*)&resid[i];
    s.x += r.x; s.y += r.y; s.z += r.z; s.w += r.w;
  }
  *(float4*)&out[i] = s;
}

// ---------------------------------------------------------------------------
// Kernel 5: RoPE in-place on fused qkv f32 buffer [M][3072]
// ---------------------------------------------------------------------------
__global__ __launch_bounds__(256) void rope_kernel(
    float* __restrict__ qkv, const int* __restrict__ pid)
{
  const int idx = blockIdx.x * 256 + threadIdx.x;
  const int total = M_ * (NH_ + NKV_) * 32;   // 2,621,440
  if (idx >= total) return;
  const int row = idx / 1280;
  const int rem = idx - row * 1280;
  const int head = rem >> 5;
  const int i = rem & 31;
  const int col = (head < NH_) ? head * 64 : 2048 + (head - NH_) * 64;
  float* base = qkv + (size_t)row * 3072 + col;
  const int pos = pid[row] + LCK_;
  const float invf = exp2f((float)i * (-13.2877123795494f / 32.0f));
  const float ang = (float)pos * invf;
  float sn, c;
  __sincosf(ang, &sn, &c);
  const float x0 = base[i];
  const float x1 = base[i + 32];
  base[i]      = x0 * c - x1 * sn;
  base[i + 32] = x1 * c + x0 * sn;
}

// ---------------------------------------------------------------------------
// Kernel 6: MFMA flash attention. Block = (b,h,qt): 64 q rows, 4 waves x 16.
// ---------------------------------------------------------------------------
__global__ __launch_bounds__(256) void attn_kernel(
    const float* __restrict__ qkv,
    const float* __restrict__ ck, const float* __restrict__ cv,
    u16* __restrict__ ao)
{
  const int bid = blockIdx.x;
  const int qt = bid & 15;
  const int bh = bid >> 4;
  const int h = bh & 31;
  const int b = bh >> 5;
  const int t = threadIdx.x;
  const int lane = t & 63;
  const int w = t >> 6;
  const int qbase = qt * 64;

  const int fr = lane & 15;            // A-frag m / B-frag n
  const int fq = (lane >> 4) * 8;      // frag k base
  const int rbase = (lane >> 4) * 4;   // C-layout row base
  const int cofs = lane & 15;          // C-layout col

  __shared__ __align__(16) u16 Qs[64 * 72];    // [qrow][d], pre-scaled bf16
  __shared__ __align__(16) u16 Ks[64 * 72];    // [key][d]
  __shared__ __align__(16) u16 Vts[64 * 72];   // [d][key]
  __shared__ __align__(16) u16 Ps[64 * 72];    // [qrow][key] per-wave slices
  __shared__ float Ls[192];

  const size_t bh_off = (size_t)b * NH_ + h;
  const float* K0 = ck + bh_off * S_ * D_;
  const float* V0 = cv + bh_off * S_ * D_;

  // stage Q once: thread t -> row sr = t>>2, d-chunk sc = (t&3)*16
  const int sr = t >> 2;
  const int sc = (t & 3) * 16;
  {
    const float* qg = qkv + (size_t)(b * S_ + qbase + sr) * 3072 + h * 64 + sc;
    float4 a = *(const float4*)&qg[0], bb = *(const float4*)&qg[4],
           c = *(const float4*)&qg[8], d = *(const float4*)&qg[12];
    a.x*=0.125f; a.y*=0.125f; a.z*=0.125f; a.w*=0.125f;
    bb.x*=0.125f; bb.y*=0.125f; bb.z*=0.125f; bb.w*=0.125f;
    c.x*=0.125f; c.y*=0.125f; c.z*=0.125f; c.w*=0.125f;
    d.x*=0.125f; d.y*=0.125f; d.z*=0.125f; d.w*=0.125f;
    bf16x8 lo, hi; cvt16(a, bb, c, d, lo, hi);
    *(bf16x8*)&Qs[sr * 72 + sc] = lo;
    *(bf16x8*)&Qs[sr * 72 + sc + 8] = hi;
  }

  float m_r[4], l_r[4];
  f32x4 Oacc[4];
  #pragma unroll
  for (int r = 0; r < 4; ++r) { m_r[r] = -3.0e38f; l_r[r] = 0.f; }
  #pragma unroll
  for (int dt = 0; dt < 4; ++dt)
    #pragma unroll
    for (int r = 0; r < 4; ++r) Oacc[dt][r] = 0.f;

  for (int kt = 0; kt <= qt; ++kt) {
    __syncthreads();   // prior QK/PV reads of Ks/Vts done
    {
      const float* kg = K0 + (size_t)(kt * 64 + sr) * D_ + sc;
      float4 a = *(const float4*)&kg[0], bb = *(const float4*)&kg[4],
             c = *(const float4*)&kg[8], d = *(const float4*)&kg[12];
      bf16x8 lo, hi; cvt16(a, bb, c, d, lo, hi);
      *(bf16x8*)&Ks[sr * 72 + sc] = lo;
      *(bf16x8*)&Ks[sr * 72 + sc + 8] = hi;
      const float* vg = V0 + (size_t)(kt * 64 + sr) * D_ + sc;
      float4 va = *(const float4*)&vg[0], vb4 = *(const float4*)&vg[4],
             vc = *(const float4*)&vg[8], vd = *(const float4*)&vg[12];
      const float vv[16] = {va.x,va.y,va.z,va.w, vb4.x,vb4.y,vb4.z,vb4.w,
                            vc.x,vc.y,vc.z,vc.w, vd.x,vd.y,vd.z,vd.w};
      #pragma unroll
      for (int i = 0; i < 16; ++i) Vts[(sc + i) * 72 + sr] = f2b(vv[i]);
    }
    __syncthreads();   // staged tiles visible

    // ---- QK^T: wave w computes S[16 rows][64 keys] ----
    const bf16x8 qa0 = *(const bf16x8*)&Qs[(w * 16 + fr) * 72 + fq];
    const bf16x8 qa1 = *(const bf16x8*)&Qs[(w * 16 + fr) * 72 + 32 + fq];
    f32x4 sacc[4];
    #pragma unroll
    for (int nt = 0; nt < 4; ++nt) {
      const bf16x8 kb0 = *(const bf16x8*)&Ks[(nt * 16 + fr) * 72 + fq];
      const bf16x8 kb1 = *(const bf16x8*)&Ks[(nt * 16 + fr) * 72 + 32 + fq];
      f32x4 z; z[0]=0.f; z[1]=0.f; z[2]=0.f; z[3]=0.f;
      z = __builtin_amdgcn_mfma_f32_16x16x32_bf16(qa0, kb0, z, 0, 0, 0);
      sacc[nt] = __builtin_amdgcn_mfma_f32_16x16x32_bf16(qa1, kb1, z, 0, 0, 0);
    }
    if (kt == qt) {   // causal mask inside diagonal tile
      #pragma unroll
      for (int nt = 0; nt < 4; ++nt) {
        const int key = nt * 16 + cofs;
        #pragma unroll
        for (int r = 0; r < 4; ++r)
          if (key > w * 16 + rbase + r) sacc[nt][r] = -3.0e38f;
      }
    }

    // ---- online softmax (per wave, rows rbase..rbase+3 of wave's 16) ----
    #pragma unroll
    for (int r = 0; r < 4; ++r) {
      float rm = fmaxf(fmaxf(sacc[0][r], sacc[1][r]), fmaxf(sacc[2][r], sacc[3][r]));
      rm = fmaxf(rm, __shfl_xor(rm, 1));
      rm = fmaxf(rm, __shfl_xor(rm, 2));
      rm = fmaxf(rm, __shfl_xor(rm, 4));
      rm = fmaxf(rm, __shfl_xor(rm, 8));
      const float mnew = fmaxf(m_r[r], rm);
      const float alpha = __expf(m_r[r] - mnew);
      float p0 = __expf(sacc[0][r] - mnew);
      float p1 = __expf(sacc[1][r] - mnew);
      float p2 = __expf(sacc[2][r] - mnew);
      float p3 = __expf(sacc[3][r] - mnew);
      float rs = p0 + p1 + p2 + p3;
      rs += __shfl_xor(rs, 1);
      rs += __shfl_xor(rs, 2);
      rs += __shfl_xor(rs, 4);
      rs += __shfl_xor(rs, 8);
      l_r[r] = l_r[r] * alpha + rs;
      m_r[r] = mnew;
      #pragma unroll
      for (int dt = 0; dt < 4; ++dt) Oacc[dt][r] *= alpha;
      u16* prow = &Ps[(w * 16 + rbase + r) * 72 + cofs];
      prow[0]  = f2b(p0);
      prow[16] = f2b(p1);
      prow[32] = f2b(p2);
      prow[48] = f2b(p3);
    }

    // ---- PV: O[16 rows][64 d] += P @ V (wave-local P, block Vts) ----
    const bf16x8 pa0 = *(const bf16x8*)&Ps[(w * 16 + fr) * 72 + fq];
    const bf16x8 pa1 = *(const bf16x8*)&Ps[(w * 16 + fr) * 72 + 32 + fq];
    #pragma unroll
    for (int dt = 0; dt < 4; ++dt) {
      const bf16x8 vb0 = *(const bf16x8*)&Vts[(dt * 16 + fr) * 72 + fq];
      const bf16x8 vb1 = *(const bf16x8*)&Vts[(dt * 16 + fr) * 72 + 32 + fq];
      Oacc[dt] = __builtin_amdgcn_mfma_f32_16x16x32_bf16(pa0, vb0, Oacc[dt], 0, 0, 0);
      Oacc[dt] = __builtin_amdgcn_mfma_f32_16x16x32_bf16(pa1, vb1, Oacc[dt], 0, 0, 0);
    }
  }

  // ---- 3 diagonal extras: logits ----
  if (t < 192) {
    const int n = t >> 6;
    const int r = t & 63;
    const int qp = qbase + r;
    const float* kp;
    if (n < 2) kp = ck + ((((size_t)(n + 1) * B_ + b) * NH_ + h) * S_ + qp) * D_;
    else       kp = qkv + (size_t)(b * S_ + qp) * 3072 + 2048 + (h >> 2) * 64;
    float e = 0.f;
    #pragma unroll 16
    for (int d = 0; d < 64; ++d) e = fmaf(b2f(Qs[r * 72 + d]), kp[d], e);
    Ls[n * 64 + r] = e;
  }
  __syncthreads();

  // ---- merge extras + normalize + store bf16 ----
  #pragma unroll
  for (int r = 0; r < 4; ++r) {
    const int qr = w * 16 + rbase + r;
    const int qp = qbase + qr;
    const float e0 = Ls[qr], e1 = Ls[64 + qr], e2 = Ls[128 + qr];
    const float mnew = fmaxf(fmaxf(m_r[r], e0), fmaxf(e1, e2));
    const float alpha = __expf(m_r[r] - mnew);
    const float p0 = __expf(e0 - mnew);
    const float p1 = __expf(e1 - mnew);
    const float p2 = __expf(e2 - mnew);
    const float inv = 1.0f / (l_r[r] * alpha + p0 + p1 + p2);
    const float* v1p = cv + ((((size_t)1 * B_ + b) * NH_ + h) * S_ + qp) * D_;
    const float* v2p = cv + ((((size_t)2 * B_ + b) * NH_ + h) * S_ + qp) * D_;
    const float* v3p = qkv + (size_t)(b * S_ + qp) * 3072 + 2560 + (h >> 2) * 64;
    u16* aorow = ao + (size_t)(b * S_ + qp) * 2048 + h * 64;
    #pragma unroll
    for (int dt = 0; dt < 4; ++dt) {
      const int col = dt * 16 + cofs;
      const float o = (Oacc[dt][r] * alpha + p0 * v1p[col] + p1 * v2p[col] + p2 * v3p[col]) * inv;
      aorow[col] = f2b(o);
    }
  }
}

// ---------------------------------------------------------------------------
extern "C" void kernel_launch(void* const* d_in, const int* in_sizes, int n_in,
                              void* d_out, int out_size, void* d_ws, size_t ws_size,
                              hipStream_t stream)
{
  const float* input_emb = (const float*)d_in[0];
  const float* hidden    = (const float*)d_in[1];
  const float* cache_k   = (const float*)d_in[2];
  const float* cache_v   = (const float*)d_in[3];
  const int*   pos_ids   = (const int*)d_in[5];
  const float* wq = (const float*)d_in[6];
  const float* wk = (const float*)d_in[7];
  const float* wv = (const float*)d_in[8];
  const float* wo = (const float*)d_in[9];
  const float* wg = (const float*)d_in[10];
  const float* wu = (const float*)d_in[11];
  const float* wd = (const float*)d_in[12];
  const float* w_hidden_norm = (const float*)d_in[13];
  const float* w_input_ln    = (const float*)d_in[14];
  const float* w_post_ln     = (const float*)d_in[15];
  float* out = (float*)d_out;

  // Workspace (bytes), peak 167.8 MiB, lifetime-aliased (see prior rounds)
  char* wsb = (char*)d_ws;
  u16*   wall   = (u16*)(wsb + 0);
  u16*   wqkv_b = wall;
  u16*   wo_b   = (u16*)(wsb + 25165824);
  u16*   wg_b   = (u16*)(wsb + 33554432);
  u16*   wu_b   = (u16*)(wsb + 67108864);
  u16*   xb     = (u16*)(wsb + 100663296);
  float* qkvf   = (float*)(wsb + 117440512);
  u16*   ao     = (u16*)(wsb + 142606336);
  float* h2     = (float*)(wsb + 150994944);
  u16*   hn     = (u16*)(wsb + 100663296);   // alias x_b
  u16*   gbb    = (u16*)(wsb + 117440512);   // alias qkvf+ao
  u16*   gub    = (u16*)(wsb + 0);           // alias wqkv_b+wo_b
  u16*   wd_b   = (u16*)(wsb + 33554432);    // alias wg_b
  float* wo_p   = (float*)(wsb + 100663296); // wo split-K partials (2x16.8M)
  float* dn_p   = (float*)(wsb + 67108864);  // down split-K partials (4x16.8M)

  // 1. weights -> bf16
  convert6_kernel<<<24576, 256, 0, stream>>>(wq, wk, wv, wo, wg, wu, wall);
  // 2. fused norms + concat -> bf16 x
  norm_concat_kernel<<<M_, 256, 0, stream>>>(input_emb, hidden, w_input_ln, w_hidden_norm, xb);
  // 3. fused QKV projection (N=3072), 256^2 tile, split-K=2 -> partials, reduce in place
  gemm256_bf16_kernel<0><<<dim3(12, 8, 2), 512, 0, stream>>>(xb, wqkv_b, qkvf, nullptr, M_, 3072, 4096);
  reduce_kernel<2><<<6144, 256, 0, stream>>>(qkvf, nullptr, qkvf, (size_t)M_ * 3072);
  // 4. RoPE in-place on qkvf
  rope_kernel<<<10240, 256, 0, stream>>>(qkvf, pos_ids);
  // 5. MFMA flash attention -> bf16 ao
  attn_kernel<<<B_ * NH_ * (S_ / 64), 256, 0, stream>>>(qkvf, cache_k, cache_v, ao);
  // 6. output projection (small N): 128^2 split-K=2; reduce + residual -> f32 h2
  gemm_bf16_kernel<0><<<dim3(16, 16, 2), 256, 0, stream>>>(ao, wo_b, wo_p, nullptr, M_, 2048, 2048);
  reduce_kernel<2><<<4096, 256, 0, stream>>>(wo_p, hidden, h2, (size_t)M_ * 2048);
  // 7. post-attention RMSNorm -> bf16 hn
  rmsnorm_kernel<<<M_, 256, 0, stream>>>(h2, w_post_ln, hn);
  // 8. gate GEMM (256^2) -> bf16 gbb
  gemm256_bf16_kernel<2><<<dim3(32, 8), 512, 0, stream>>>(hn, wg_b, gbb, nullptr, M_, 8192, 2048);
  // 9. wd -> bf16 (wg_b region now dead)
  convert1_kernel<<<8192, 256, 0, stream>>>(wd, wd_b);
  // 10. up GEMM (256^2), epilogue silu(gate)*up -> bf16 gub
  gemm256_bf16_kernel<3><<<dim3(32, 8), 512, 0, stream>>>(hn, wu_b, gub, gbb, M_, 8192, 2048);
  // 11. down GEMM (256^2) split-K=4 -> partials; reduce + residual(h2) -> out f32
  gemm256_bf16_kernel<0><<<dim3(8, 8, 4), 512, 0, stream>>>(gub, wd_b, dn_p, nullptr, M_, 2048, 8192);
  reduce_kernel<4><<<4096, 256, 0, stream>>>(dn_p, h2, out, (size_t)M_ * 2048);
}